// Round 16
// baseline (626.602 us; speedup 1.0000x reference)
//
#include <hip/hip_runtime.h>
#include <hip/hip_bf16.h>

// ---------------------------------------------------------------------------
// MiniTransformer: B=8,S=2048,D=1024,H=2048, fp32 in/out, bf16 MFMA inside.
// GEMM R16: revert to the PROVEN m97/m103 simple structure (912 TF @4k):
// 128x128 tile, BK=64, 4 waves (2x2, 64x64/wave), SINGLE-buffer 32KB LDS,
// plain __syncthreads() pair per K-tile, global_load_lds w16, 16x16x32 MFMA,
// verified 0-conflict XOR chunk layout (slot=(c)^(row&7) involution).
// Rationale: 256'/128KB config = 1 block/CU -> intra-block waits fully
// exposed (MfmaUtil stuck 33% across R8-R15). 128'/32KB + ~164 regs -> 3
// blocks/CU; cross-block overlap (m114) hides barrier drains; ladder
// measured 128'=912 > 256'=792 TF at this structure (m103/m112).
// Pipeline: cvt, QKV(fused, vT epilogue), scores, cvtW, softmax, PV+res,
// LN1, FF1(bias+relu), FF2(bias+res), LN2. Scratch 234,881,024 B.
// ---------------------------------------------------------------------------

typedef __attribute__((ext_vector_type(4))) float  f32x4;
typedef __attribute__((ext_vector_type(8))) short  short8;
typedef __attribute__((ext_vector_type(4))) short  short4v;
typedef __attribute__((ext_vector_type(8))) __bf16 bf16x8;
typedef unsigned short ushort_t;

static __device__ __forceinline__ unsigned short f2bf(float f) {
  unsigned u = __builtin_bit_cast(unsigned, f);
  u += 0x7fffu + ((u >> 16) & 1u);  // RNE
  return (unsigned short)(u >> 16);
}
static __device__ __forceinline__ float bf2f(unsigned short u) {
  return __builtin_bit_cast(float, (unsigned)u << 16);
}

#define GLDS16(g, l)                                                        \
  __builtin_amdgcn_global_load_lds(                                         \
      (const __attribute__((address_space(1))) void*)(g),                   \
      (__attribute__((address_space(3))) void*)(l), 16, 0, 0)

// ---------------------------------------------------------------------------
__global__ __launch_bounds__(256) void cvt_f32_bf16(
    const float* __restrict__ in, ushort_t* __restrict__ out, long n) {
  long i = ((long)blockIdx.x * 256 + threadIdx.x) * 8;
  if (i >= n) return;
  f32x4 a = *(const f32x4*)(in + i);
  f32x4 b = *(const f32x4*)(in + i + 4);
  short8 t;
  t[0] = (short)f2bf(a.x); t[1] = (short)f2bf(a.y);
  t[2] = (short)f2bf(a.z); t[3] = (short)f2bf(a.w);
  t[4] = (short)f2bf(b.x); t[5] = (short)f2bf(b.y);
  t[6] = (short)f2bf(b.z); t[7] = (short)f2bf(b.w);
  *(short8*)(out + i) = t;
}

// ---------------------------------------------------------------------------
enum { EP_QKV = 0, EP_BF16 = 1, EP_PV = 2, EP_FF1 = 3, EP_FF2 = 4 };

constexpr long BSDc = 8L * 2048 * 1024;

template <int EPI>
__global__ __launch_bounds__(256) void gemm_bt(
    const ushort_t* __restrict__ A, const ushort_t* __restrict__ B,
    void* __restrict__ C, int N, int K, long sA, long sB, long sC, long sRes,
    const float* __restrict__ bias, const float* __restrict__ res,
    float scale) {
  // Single-buffer LDS: A,B tiles [128 rows][64 k] bf16 = 16KB each (32KB).
  __shared__ __align__(16) ushort_t As[8192];
  __shared__ __align__(16) ushort_t Bs[8192];
  const int tid  = threadIdx.x;
  const int lane = tid & 63;
  const int w    = tid >> 6;        // 0..3
  const int wr   = (w >> 1) * 64;   // wave row base
  const int wc   = (w & 1) * 64;    // wave col base
  const int l15  = lane & 15;
  const int hi   = lane >> 4;       // 0..3 : 8-elem k-chunk
  const long bz  = blockIdx.z;
  const long m0  = (long)blockIdx.x * 128;
  const long n0  = (long)blockIdx.y * 128;
  const ushort_t* Ab = A + bz * sA;
  const ushort_t* Bb = B + bz * sB;

  // Staging source (inverse of read-side XOR). Chunk P = it*256 + tid
  // (16B each): row = P>>3, slot = (P&7)^(row&7); elem off = row*K + slot*8.
  long aoff[4], boff[4];
#pragma unroll
  for (int it = 0; it < 4; ++it) {
    int P  = it * 256 + tid;
    int r  = P >> 3;
    int sl = (P & 7) ^ (r & 7);
    aoff[it] = (m0 + r) * (long)K + sl * 8;
    boff[it] = (n0 + r) * (long)K + sl * 8;
  }

  // Read-side swizzled byte offsets (k-step 0 / 1), lane-constant.
  // frag row = base + l15 (bases mult. of 16 -> row&7 == l15&7);
  // byte = row*128 + ((kk*4+hi)^(l15&7))*16.
  const int ab0 = l15 * 128 + ((hi) ^ (l15 & 7)) * 16;
  const int ab1 = l15 * 128 + ((4 + hi) ^ (l15 & 7)) * 16;

  f32x4 acc[4][4] = {};

  for (int k0 = 0; k0 < K; k0 += 64) {
    __syncthreads();
#pragma unroll
    for (int it = 0; it < 4; ++it)
      GLDS16(Ab + aoff[it] + k0, As + ((it * 256 + w * 64) << 3));
#pragma unroll
    for (int it = 0; it < 4; ++it)
      GLDS16(Bb + boff[it] + k0, Bs + ((it * 256 + w * 64) << 3));
    __syncthreads();
    const char* Ah = (const char*)As + wr * 128;
    const char* Bh = (const char*)Bs + wc * 128;
#pragma unroll
    for (int kk = 0; kk < 2; ++kk) {
      const int ab = kk ? ab1 : ab0;
      short8 afr[4], bfr[4];
#pragma unroll
      for (int i = 0; i < 4; ++i) {
        afr[i] = *(const short8*)(Ah + i * 2048 + ab);
        bfr[i] = *(const short8*)(Bh + i * 2048 + ab);
      }
#pragma unroll
      for (int i = 0; i < 4; ++i)
#pragma unroll
        for (int j = 0; j < 4; ++j)
          acc[i][j] = __builtin_amdgcn_mfma_f32_16x16x32_bf16(
              __builtin_bit_cast(bf16x8, afr[i]),
              __builtin_bit_cast(bf16x8, bfr[j]), acc[i][j], 0, 0, 0);
    }
  }

  // Epilogue. C/D layout: col = lane&15, row = (lane>>4)*4 + reg.
  const int rb0 = hi << 2;
  const int cl  = l15;
#pragma unroll
  for (int i = 0; i < 4; ++i) {
#pragma unroll
    for (int j = 0; j < 4; ++j) {
      long gmb = m0 + wr + i * 16 + rb0;
      long gc  = n0 + wc + j * 16 + cl;
      if constexpr (EPI == EP_QKV) {
        long which = gc >> 10;  // 0=q, 1=k, 2=v (uniform per block)
        long col   = gc & 1023;
        if (which == 2) {
          long bb = gmb >> 11, s = gmb & 2047;
          short4v pk;
#pragma unroll
          for (int r = 0; r < 4; ++r) pk[r] = (short)f2bf(acc[i][j][r]);
          *(short4v*)((ushort_t*)C + 2 * BSDc + ((bb << 10) + col) * 2048 + s) =
              pk;
        } else {
#pragma unroll
          for (int r = 0; r < 4; ++r)
            ((ushort_t*)C)[which * BSDc + (gmb + r) * 1024 + col] =
                f2bf(acc[i][j][r]);
        }
      } else {
#pragma unroll
        for (int r = 0; r < 4; ++r) {
          long gm = gmb + r;
          float v = acc[i][j][r] * scale;
          if constexpr (EPI == EP_BF16) {
            ((ushort_t*)C)[bz * sC + gm * N + gc] = f2bf(v);
          } else if constexpr (EPI == EP_PV) {
            v += res[bz * sRes + gm * N + gc];
            ((float*)C)[bz * sC + gm * N + gc] = v;
          } else if constexpr (EPI == EP_FF1) {
            v += bias[gc];
            v = v > 0.f ? v : 0.f;
            ((ushort_t*)C)[gm * N + gc] = f2bf(v);
          } else {  // EP_FF2
            v += bias[gc] + res[gm * N + gc];
            ((float*)C)[gm * N + gc] = v;
          }
        }
      }
    }
  }
}

// ---------------------------------------------------------------------------
__global__ __launch_bounds__(256) void softmax_inplace(
    ushort_t* __restrict__ P) {
  __shared__ float rmax[4], rsum[4];
  const int tid   = threadIdx.x;
  const long base = (long)blockIdx.x * 2048;
  short8 sv = *(const short8*)(P + base + tid * 8);
  float v[8];
#pragma unroll
  for (int j = 0; j < 8; ++j) v[j] = bf2f((unsigned short)sv[j]);
  float mx = v[0];
#pragma unroll
  for (int j = 1; j < 8; ++j) mx = fmaxf(mx, v[j]);
#pragma unroll
  for (int off = 32; off; off >>= 1) mx = fmaxf(mx, __shfl_down(mx, off, 64));
  if ((tid & 63) == 0) rmax[tid >> 6] = mx;
  __syncthreads();
  mx = fmaxf(fmaxf(rmax[0], rmax[1]), fmaxf(rmax[2], rmax[3]));
  float s = 0.f;
#pragma unroll
  for (int j = 0; j < 8; ++j) {
    v[j] = __expf(v[j] - mx);
    s += v[j];
  }
#pragma unroll
  for (int off = 32; off; off >>= 1) s += __shfl_down(s, off, 64);
  if ((tid & 63) == 0) rsum[tid >> 6] = s;
  __syncthreads();
  s = (rsum[0] + rsum[1]) + (rsum[2] + rsum[3]);
  float inv = 1.f / s;
  short8 o;
#pragma unroll
  for (int j = 0; j < 8; ++j) o[j] = (short)f2bf(v[j] * inv);
  *(short8*)(P + base + tid * 8) = o;
}

// ---------------------------------------------------------------------------
template <int MODE>
__global__ __launch_bounds__(256) void ln_row(const float* __restrict__ X,
                                              const float* __restrict__ g,
                                              const float* __restrict__ be,
                                              float* __restrict__ Yf,
                                              ushort_t* __restrict__ Yb) {
  __shared__ float rs[4], rq[4];
  const int tid   = threadIdx.x;
  const long base = (long)blockIdx.x << 10;
  f32x4 v = *(const f32x4*)(X + base + tid * 4);
  float s = v.x + v.y + v.z + v.w;
  float q = v.x * v.x + v.y * v.y + v.z * v.z + v.w * v.w;
#pragma unroll
  for (int off = 32; off; off >>= 1) {
    s += __shfl_down(s, off, 64);
    q += __shfl_down(q, off, 64);
  }
  if ((tid & 63) == 0) {
    rs[tid >> 6] = s;
    rq[tid >> 6] = q;
  }
  __syncthreads();
  s = (rs[0] + rs[1]) + (rs[2] + rs[3]);
  q = (rq[0] + rq[1]) + (rq[2] + rq[3]);
  float mu   = s * (1.f / 1024.f);
  float var  = q * (1.f / 1024.f) - mu * mu;
  float rstd = rsqrtf(var + 1e-5f);
  int c    = tid * 4;
  f32x4 gg = *(const f32x4*)(g + c);
  f32x4 bb = *(const f32x4*)(be + c);
  f32x4 y;
  y.x = (v.x - mu) * rstd * gg.x + bb.x;
  y.y = (v.y - mu) * rstd * gg.y + bb.y;
  y.z = (v.z - mu) * rstd * gg.z + bb.z;
  y.w = (v.w - mu) * rstd * gg.w + bb.w;
  *(f32x4*)(Yf + base + c) = y;
  if constexpr (MODE == 0) {
    short4v ob;
    ob[0] = (short)f2bf(y.x);
    ob[1] = (short)f2bf(y.y);
    ob[2] = (short)f2bf(y.z);
    ob[3] = (short)f2bf(y.w);
    *(short4v*)(Yb + base + c) = ob;
  }
}

// ---------------------------------------------------------------------------
extern "C" void kernel_launch(void* const* d_in, const int* in_sizes, int n_in,
                              void* d_out, int out_size, void* d_ws,
                              size_t ws_size, hipStream_t stream) {
  const float* x   = (const float*)d_in[0];
  const float* Wq  = (const float*)d_in[1];
  const float* Wk  = (const float*)d_in[2];
  const float* Wv  = (const float*)d_in[3];
  const float* W1  = (const float*)d_in[4];
  const float* b1  = (const float*)d_in[5];
  const float* W2  = (const float*)d_in[6];
  const float* b2  = (const float*)d_in[7];
  const float* g1  = (const float*)d_in[8];
  const float* be1 = (const float*)d_in[9];
  const float* g2  = (const float*)d_in[10];
  const float* be2 = (const float*)d_in[11];
  float* out = (float*)d_out;

  constexpr long BSD = 8L * 2048 * 1024;
  constexpr long BSS = 8L * 2048 * 2048;
  constexpr long DD  = 1024L * 1024;
  constexpr long HD  = 2048L * 1024;

  // Scratch: qb | kb | vTb | sP | r1  = 234,881,024 bytes total.
  ushort_t* qb  = (ushort_t*)d_ws;
  ushort_t* kb  = qb + BSD;
  ushort_t* vTb = kb + BSD;
  ushort_t* sP  = vTb + BSD;
  float*    r1  = (float*)(sP + BSS);

  ushort_t* xb    = sP;              // dead before scores written
  ushort_t* Wqkvb = (ushort_t*)r1;   // dead before PV writes r1
  ushort_t* W1b   = kb;              // converted after scores GEMM
  ushort_t* W2b   = kb + HD;
  ushort_t* hb    = qb;
  float*    h     = out;             // d_out dead until LN2 rewrites it

  dim3 blk(256);
  const long SD = 2048L * 1024, SS = 2048L * 2048, DS = 1024L * 2048;

  // 0: conversions
  cvt_f32_bf16<<<dim3(8192), blk, 0, stream>>>(x, xb, BSD);
  cvt_f32_bf16<<<dim3(512), blk, 0, stream>>>(Wq, Wqkvb, DD);
  cvt_f32_bf16<<<dim3(512), blk, 0, stream>>>(Wk, Wqkvb + DD, DD);
  cvt_f32_bf16<<<dim3(512), blk, 0, stream>>>(Wv, Wqkvb + 2 * DD, DD);
  // 1: fused QKV projection (M=16384, N=3072, K=1024)
  gemm_bt<EP_QKV><<<dim3(128, 24, 1), blk, 0, stream>>>(
      xb, Wqkvb, qb, 3072, 1024, 0, 0, 0, 0, nullptr, nullptr, 1.f);
  // 2: scores = q@k^T / 32 (per batch: M=N=2048, K=1024)
  gemm_bt<EP_BF16><<<dim3(16, 16, 8), blk, 0, stream>>>(
      qb, kb, sP, 2048, 1024, SD, SD, SS, 0, nullptr, nullptr, 0.03125f);
  // 2b: FFN weights into kb region (kb dead now)
  cvt_f32_bf16<<<dim3(1024), blk, 0, stream>>>(W1, W1b, HD);
  cvt_f32_bf16<<<dim3(1024), blk, 0, stream>>>(W2, W2b, HD);
  // 3: softmax
  softmax_inplace<<<dim3(16384), blk, 0, stream>>>(sP);
  // 4: attn_out + x (per batch: M=2048, N=1024, K=2048)
  gemm_bt<EP_PV><<<dim3(16, 8, 8), blk, 0, stream>>>(
      sP, vTb, r1, 1024, 2048, SS, DS, SD, SD, nullptr, x, 1.f);
  // 5: LN1 -> h (fp32, in d_out) + hb (bf16, aliases qb)
  ln_row<0><<<dim3(16384), blk, 0, stream>>>(r1, g1, be1, h, hb);
  // 6: ff1 = relu(hb@W1^T + b1) (M=16384, N=2048, K=1024)
  gemm_bt<EP_FF1><<<dim3(128, 16, 1), blk, 0, stream>>>(
      hb, W1b, sP, 2048, 1024, 0, 0, 0, 0, b1, nullptr, 1.f);
  // 7: res2 = ff1@W2^T + b2 + h (M=16384, N=1024, K=2048)
  gemm_bt<EP_FF2><<<dim3(128, 8, 1), blk, 0, stream>>>(
      sP, W2b, r1, 1024, 2048, 0, 0, 0, 0, b2, h, 1.f);
  // 8: LN2 -> out (overwrites h)
  ln_row<1><<<dim3(16384), blk, 0, stream>>>(r1, g2, be2, out, nullptr);
}

// Round 17
// 522.726 us; speedup vs baseline: 1.1987x; 1.1987x over previous
//
#include <hip/hip_runtime.h>
#include <hip/hip_bf16.h>

// ---------------------------------------------------------------------------
// MiniTransformer: B=8,S=2048,D=1024,H=2048, fp32 in/out, bf16 MFMA inside.
// GEMM R17: R15 ring + TRIPLE-BUFFERED B -> single barrier per K-tile.
// 256x256 tile, BK=64, 8 waves (2Mx4N), 16x16x32 MFMA.
// LDS: As[2][2][8192] (64KB) + Bs[3][2][8192] (96KB) = 160KB (CU max).
// Per tile u (d=u&1, b3=u%3): reads As[d], Bs[b3]; stages A(u+1)->As[d~]
// (ph1,ph2) and B(u+2)->Bs[(u+2)%3] (ph3,ph4). WAR: As[d~] last read tile
// u-1 (boundary barrier separates); Bs[(u+2)%3] last read tile u-1 (ditto)
// -> NO mid-tile barrier needed; waves drift freely across all 4 phases,
// so one wave's MFMA covers siblings' LDS drains (pipes were measured
// serialized: MFMA 2483 + LDS 2304 + VALU 1470 ~= wall 7350 cy/tile).
// Ledger: boundary outstanding = B(u+1):4(oldest), A(u+1):4, B(u+2):4;
// vmcnt(4) retires B(u+1)+A(u+1) exactly. Prologue B(0),A(0),B(1)=12 ->
// vmcnt(4). Tail: u+2>=NT -> vmcnt(0). Never drains mid-steady-state.
// LDS XOR chunk layout (0 conflicts) and everything else = R15.
// Pipeline: cvt, QKV, scores, cvtW, softmax, PV, LN1, FF1, FF2, LN2.
// Scratch 234,881,024 B.
// ---------------------------------------------------------------------------

typedef __attribute__((ext_vector_type(4))) float  f32x4;
typedef __attribute__((ext_vector_type(8))) short  short8;
typedef __attribute__((ext_vector_type(4))) short  short4v;
typedef __attribute__((ext_vector_type(8))) __bf16 bf16x8;
typedef unsigned short ushort_t;

static __device__ __forceinline__ unsigned short f2bf(float f) {
  unsigned u = __builtin_bit_cast(unsigned, f);
  u += 0x7fffu + ((u >> 16) & 1u);  // RNE
  return (unsigned short)(u >> 16);
}
static __device__ __forceinline__ float bf2f(unsigned short u) {
  return __builtin_bit_cast(float, (unsigned)u << 16);
}

#define GLDS16(g, l)                                                        \
  __builtin_amdgcn_global_load_lds(                                         \
      (const __attribute__((address_space(1))) void*)(g),                   \
      (__attribute__((address_space(3))) void*)(l), 16, 0, 0)

// ---------------------------------------------------------------------------
__global__ __launch_bounds__(256) void cvt_f32_bf16(
    const float* __restrict__ in, ushort_t* __restrict__ out, long n) {
  long i = ((long)blockIdx.x * 256 + threadIdx.x) * 8;
  if (i >= n) return;
  f32x4 a = *(const f32x4*)(in + i);
  f32x4 b = *(const f32x4*)(in + i + 4);
  short8 t;
  t[0] = (short)f2bf(a.x); t[1] = (short)f2bf(a.y);
  t[2] = (short)f2bf(a.z); t[3] = (short)f2bf(a.w);
  t[4] = (short)f2bf(b.x); t[5] = (short)f2bf(b.y);
  t[6] = (short)f2bf(b.z); t[7] = (short)f2bf(b.w);
  *(short8*)(out + i) = t;
}

// ---------------------------------------------------------------------------
enum { EP_QKV = 0, EP_BF16 = 1, EP_PV = 2, EP_FF1 = 3, EP_FF2 = 4 };

constexpr long BSDc = 8L * 2048 * 1024;

template <int EPI>
__global__ __launch_bounds__(512, 2) void gemm_bt(
    const ushort_t* __restrict__ A, const ushort_t* __restrict__ B,
    void* __restrict__ C, int N, int K, long sA, long sB, long sC, long sRes,
    const float* __restrict__ bias, const float* __restrict__ res,
    float scale) {
  __shared__ __align__(16) ushort_t As[2][2][8192];   // 64KB
  __shared__ __align__(16) ushort_t Bs[3][2][8192];   // 96KB
  const int tid  = threadIdx.x;
  const int lane = tid & 63;
  const int w    = tid >> 6;        // 0..7
  const int wm   = w >> 2;          // 0..1 : wave row-half (128 rows)
  const int wn   = w & 3;           // 0..3 : wave col (64 cols)
  const int l15  = lane & 15;
  const int hi   = lane >> 4;       // 0..3 : 8-elem k-chunk
  const long bz  = blockIdx.z;
  const long m0  = (long)blockIdx.x * 256;
  const long n0  = (long)blockIdx.y * 256;
  const ushort_t* Ab = A + bz * sA;
  const ushort_t* Bb = B + bz * sB;

  // Staging source (inverse of read-side XOR): thread handles phys chunks
  // tid and tid+512 of each 1024-chunk half. row = P>>3, slot = (P&7)^(row&7).
  const int srow = tid >> 3;
  const int sc   = (tid & 7) ^ (srow & 7);
  const long offA0 = (m0 + srow) * (long)K + sc * 8;
  const long offB0 = (n0 + srow) * (long)K + sc * 8;
  const int dst0 = w * 512;
  const int dst1 = 4096 + w * 512;

#define STAGE_A(t, h)                                                       \
  {                                                                         \
    const long o_ = (long)(t) * 64 + (long)(h) * 128 * K;                   \
    ushort_t* l_ = &As[(t) & 1][h][0];                                      \
    GLDS16(Ab + offA0 + o_, l_ + dst0);                                     \
    GLDS16(Ab + offA0 + 64 * (long)K + o_, l_ + dst1);                      \
  }
#define STAGE_B(t, h, buf)                                                  \
  {                                                                         \
    const long o_ = (long)(t) * 64 + (long)(h) * 128 * K;                   \
    ushort_t* l_ = &Bs[buf][h][0];                                          \
    GLDS16(Bb + offB0 + o_, l_ + dst0);                                     \
    GLDS16(Bb + offB0 + 64 * (long)K + o_, l_ + dst1);                      \
  }

  // Read-side swizzled byte offsets (k-step 0 / 1), lane-constant.
  const int ab0 = l15 * 128 + ((hi) ^ (l15 & 7)) * 16;
  const int ab1 = l15 * 128 + ((4 + hi) ^ (l15 & 7)) * 16;

#define READ_A(ai)                                                          \
  _Pragma("unroll") for (int i = 0; i < 4; ++i) {                           \
    afr[i][0] = *(const short8*)(Ah + (ai) * 8192 + i * 2048 + ab0);        \
    afr[i][1] = *(const short8*)(Ah + (ai) * 8192 + i * 2048 + ab1);        \
  }
#define READ_B(bj)                                                          \
  _Pragma("unroll") for (int j = 0; j < 2; ++j) {                           \
    bfr[bj][j][0] = *(const short8*)(Bh + (bj) * 4096 + j * 2048 + ab0);    \
    bfr[bj][j][1] = *(const short8*)(Bh + (bj) * 4096 + j * 2048 + ab1);    \
  }
#define QMFMA(ib, jb, bsel)                                                 \
  _Pragma("unroll") for (int i = 0; i < 4; ++i)                             \
  _Pragma("unroll") for (int j = 0; j < 2; ++j)                             \
  _Pragma("unroll") for (int ks = 0; ks < 2; ++ks)                          \
    acc[(ib) + i][(jb) + j] = __builtin_amdgcn_mfma_f32_16x16x32_bf16(      \
        __builtin_bit_cast(bf16x8, afr[i][ks]),                             \
        __builtin_bit_cast(bf16x8, bfr[bsel][j][ks]),                       \
        acc[(ib) + i][(jb) + j], 0, 0, 0);

  f32x4 acc[8][4] = {};
  const int NT = K >> 6;  // K-tiles of 64 (16 or 32)

  // Prologue: B(0)->Bs[0], A(0), B(1)->Bs[1] = 12 loads; retire B0+A0.
  STAGE_B(0, 0, 0) STAGE_B(0, 1, 0) STAGE_A(0, 0) STAGE_A(0, 1)
  STAGE_B(1, 0, 1) STAGE_B(1, 1, 1)
  asm volatile("s_waitcnt vmcnt(4)" ::: "memory");
  __builtin_amdgcn_sched_barrier(0);
  __builtin_amdgcn_s_barrier();
  __builtin_amdgcn_sched_barrier(0);

  int b3 = 0;  // u % 3
  for (int u = 0; u < NT; ++u) {
    const int d    = u & 1;
    const int b3p2 = b3 >= 1 ? b3 - 1 : 2;  // (u+2) % 3
    const char* Ah = (const char*)&As[d][wm][0];
    const char* Bh = (const char*)&Bs[b3][wn >> 1][0] + (wn & 1) * 8192;
    short8 afr[4][2], bfr[2][2][2];
    // ---- phase 1: quadrant A0 x B0 ----
    READ_A(0)
    READ_B(0)
    if (u + 1 < NT) STAGE_A(u + 1, 0)
    QMFMA(0, 0, 0)
    // ---- phase 2: quadrant A0 x B1 ----
    READ_B(1)
    if (u + 1 < NT) STAGE_A(u + 1, 1)
    QMFMA(0, 2, 1)
    // ---- phase 3: quadrant A1 x B1 (B(u+2) -> Bs[(u+2)%3], untouched) ----
    READ_A(1)
    if (u + 2 < NT) STAGE_B(u + 2, 0, b3p2)
    QMFMA(4, 2, 1)
    // ---- phase 4: quadrant A1 x B0 (all from regs) ----
    if (u + 2 < NT) STAGE_B(u + 2, 1, b3p2)
    QMFMA(4, 0, 0)
    // ---- K-tile boundary (the ONLY barrier per tile) ----
    if (u + 1 < NT) {
      if (u + 2 < NT) {
        asm volatile("s_waitcnt vmcnt(4)" ::: "memory");
      } else {
        asm volatile("s_waitcnt vmcnt(0)" ::: "memory");
      }
      __builtin_amdgcn_sched_barrier(0);
      __builtin_amdgcn_s_barrier();
      __builtin_amdgcn_sched_barrier(0);
    }
    b3 = b3 == 2 ? 0 : b3 + 1;
  }
#undef STAGE_A
#undef STAGE_B
#undef READ_A
#undef READ_B
#undef QMFMA

  // Epilogue. C/D layout: col = lane&15, row = (lane>>4)*4 + reg.
  const int rb0 = hi << 2;
  const int cl  = l15;
#pragma unroll
  for (int i = 0; i < 8; ++i) {
#pragma unroll
    for (int j = 0; j < 4; ++j) {
      long gmb = m0 + wm * 128 + i * 16 + rb0;
      long gc  = n0 + wn * 64 + j * 16 + cl;
      if constexpr (EPI == EP_QKV) {
        long which = gc >> 10;  // 0=q, 1=k, 2=v (uniform per block)
        long col   = gc & 1023;
        if (which == 2) {
          long bb = gmb >> 11, s = gmb & 2047;
          short4v pk;
#pragma unroll
          for (int r = 0; r < 4; ++r) pk[r] = (short)f2bf(acc[i][j][r]);
          *(short4v*)((ushort_t*)C + 2 * BSDc + ((bb << 10) + col) * 2048 + s) =
              pk;
        } else {
#pragma unroll
          for (int r = 0; r < 4; ++r)
            ((ushort_t*)C)[which * BSDc + (gmb + r) * 1024 + col] =
                f2bf(acc[i][j][r]);
        }
      } else {
#pragma unroll
        for (int r = 0; r < 4; ++r) {
          long gm = gmb + r;
          float v = acc[i][j][r] * scale;
          if constexpr (EPI == EP_BF16) {
            ((ushort_t*)C)[bz * sC + gm * N + gc] = f2bf(v);
          } else if constexpr (EPI == EP_PV) {
            v += res[bz * sRes + gm * N + gc];
            ((float*)C)[bz * sC + gm * N + gc] = v;
          } else if constexpr (EPI == EP_FF1) {
            v += bias[gc];
            v = v > 0.f ? v : 0.f;
            ((ushort_t*)C)[gm * N + gc] = f2bf(v);
          } else {  // EP_FF2
            v += bias[gc] + res[gm * N + gc];
            ((float*)C)[gm * N + gc] = v;
          }
        }
      }
    }
  }
}

// ---------------------------------------------------------------------------
__global__ __launch_bounds__(256) void softmax_inplace(
    ushort_t* __restrict__ P) {
  __shared__ float rmax[4], rsum[4];
  const int tid   = threadIdx.x;
  const long base = (long)blockIdx.x * 2048;
  short8 sv = *(const short8*)(P + base + tid * 8);
  float v[8];
#pragma unroll
  for (int j = 0; j < 8; ++j) v[j] = bf2f((unsigned short)sv[j]);
  float mx = v[0];
#pragma unroll
  for (int j = 1; j < 8; ++j) mx = fmaxf(mx, v[j]);
#pragma unroll
  for (int off = 32; off; off >>= 1) mx = fmaxf(mx, __shfl_down(mx, off, 64));
  if ((tid & 63) == 0) rmax[tid >> 6] = mx;
  __syncthreads();
  mx = fmaxf(fmaxf(rmax[0], rmax[1]), fmaxf(rmax[2], rmax[3]));
  float s = 0.f;
#pragma unroll
  for (int j = 0; j < 8; ++j) {
    v[j] = __expf(v[j] - mx);
    s += v[j];
  }
#pragma unroll
  for (int off = 32; off; off >>= 1) s += __shfl_down(s, off, 64);
  if ((tid & 63) == 0) rsum[tid >> 6] = s;
  __syncthreads();
  s = (rsum[0] + rsum[1]) + (rsum[2] + rsum[3]);
  float inv = 1.f / s;
  short8 o;
#pragma unroll
  for (int j = 0; j < 8; ++j) o[j] = (short)f2bf(v[j] * inv);
  *(short8*)(P + base + tid * 8) = o;
}

// ---------------------------------------------------------------------------
template <int MODE>
__global__ __launch_bounds__(256) void ln_row(const float* __restrict__ X,
                                              const float* __restrict__ g,
                                              const float* __restrict__ be,
                                              float* __restrict__ Yf,
                                              ushort_t* __restrict__ Yb) {
  __shared__ float rs[4], rq[4];
  const int tid   = threadIdx.x;
  const long base = (long)blockIdx.x << 10;
  f32x4 v = *(const f32x4*)(X + base + tid * 4);
  float s = v.x + v.y + v.z + v.w;
  float q = v.x * v.x + v.y * v.y + v.z * v.z + v.w * v.w;
#pragma unroll
  for (int off = 32; off; off >>= 1) {
    s += __shfl_down(s, off, 64);
    q += __shfl_down(q, off, 64);
  }
  if ((tid & 63) == 0) {
    rs[tid >> 6] = s;
    rq[tid >> 6] = q;
  }
  __syncthreads();
  s = (rs[0] + rs[1]) + (rs[2] + rs[3]);
  q = (rq[0] + rq[1]) + (rq[2] + rq[3]);
  float mu   = s * (1.f / 1024.f);
  float var  = q * (1.f / 1024.f) - mu * mu;
  float rstd = rsqrtf(var + 1e-5f);
  int c    = tid * 4;
  f32x4 gg = *(const f32x4*)(g + c);
  f32x4 bb = *(const f32x4*)(be + c);
  f32x4 y;
  y.x = (v.x - mu) * rstd * gg.x + bb.x;
  y.y = (v.y - mu) * rstd * gg.y + bb.y;
  y.z = (v.z - mu) * rstd * gg.z + bb.z;
  y.w = (v.w - mu) * rstd * gg.w + bb.w;
  *(f32x4*)(Yf + base + c) = y;
  if constexpr (MODE == 0) {
    short4v ob;
    ob[0] = (short)f2bf(y.x);
    ob[1] = (short)f2bf(y.y);
    ob[2] = (short)f2bf(y.z);
    ob[3] = (short)f2bf(y.w);
    *(short4v*)(Yb + base + c) = ob;
  }
}

// ---------------------------------------------------------------------------
extern "C" void kernel_launch(void* const* d_in, const int* in_sizes, int n_in,
                              void* d_out, int out_size, void* d_ws,
                              size_t ws_size, hipStream_t stream) {
  const float* x   = (const float*)d_in[0];
  const float* Wq  = (const float*)d_in[1];
  const float* Wk  = (const float*)d_in[2];
  const float* Wv  = (const float*)d_in[3];
  const float* W1  = (const float*)d_in[4];
  const float* b1  = (const float*)d_in[5];
  const float* W2  = (const float*)d_in[6];
  const float* b2  = (const float*)d_in[7];
  const float* g1  = (const float*)d_in[8];
  const float* be1 = (const float*)d_in[9];
  const float* g2  = (const float*)d_in[10];
  const float* be2 = (const float*)d_in[11];
  float* out = (float*)d_out;

  constexpr long BSD = 8L * 2048 * 1024;
  constexpr long BSS = 8L * 2048 * 2048;
  constexpr long DD  = 1024L * 1024;
  constexpr long HD  = 2048L * 1024;

  // Scratch: qb | kb | vTb | sP | r1  = 234,881,024 bytes total.
  ushort_t* qb  = (ushort_t*)d_ws;
  ushort_t* kb  = qb + BSD;
  ushort_t* vTb = kb + BSD;
  ushort_t* sP  = vTb + BSD;
  float*    r1  = (float*)(sP + BSS);

  ushort_t* xb    = sP;              // dead before scores written
  ushort_t* Wqkvb = (ushort_t*)r1;   // dead before PV writes r1
  ushort_t* W1b   = kb;              // converted after scores GEMM
  ushort_t* W2b   = kb + HD;
  ushort_t* hb    = qb;
  float*    h     = out;             // d_out dead until LN2 rewrites it

  dim3 blk(256), gblk(512);
  const long SD = 2048L * 1024, SS = 2048L * 2048, DS = 1024L * 2048;

  // 0: conversions
  cvt_f32_bf16<<<dim3(8192), blk, 0, stream>>>(x, xb, BSD);
  cvt_f32_bf16<<<dim3(512), blk, 0, stream>>>(Wq, Wqkvb, DD);
  cvt_f32_bf16<<<dim3(512), blk, 0, stream>>>(Wk, Wqkvb + DD, DD);
  cvt_f32_bf16<<<dim3(512), blk, 0, stream>>>(Wv, Wqkvb + 2 * DD, DD);
  // 1: fused QKV projection (M=16384, N=3072, K=1024)
  gemm_bt<EP_QKV><<<dim3(64, 12, 1), gblk, 0, stream>>>(
      xb, Wqkvb, qb, 3072, 1024, 0, 0, 0, 0, nullptr, nullptr, 1.f);
  // 2: scores = q@k^T / 32 (per batch: M=N=2048, K=1024)
  gemm_bt<EP_BF16><<<dim3(8, 8, 8), gblk, 0, stream>>>(
      qb, kb, sP, 2048, 1024, SD, SD, SS, 0, nullptr, nullptr, 0.03125f);
  // 2b: FFN weights into kb region (kb dead now)
  cvt_f32_bf16<<<dim3(1024), blk, 0, stream>>>(W1, W1b, HD);
  cvt_f32_bf16<<<dim3(1024), blk, 0, stream>>>(W2, W2b, HD);
  // 3: softmax
  softmax_inplace<<<dim3(16384), blk, 0, stream>>>(sP);
  // 4: attn_out + x (per batch: M=2048, N=1024, K=2048)
  gemm_bt<EP_PV><<<dim3(8, 4, 8), gblk, 0, stream>>>(
      sP, vTb, r1, 1024, 2048, SS, DS, SD, SD, nullptr, x, 1.f);
  // 5: LN1 -> h (fp32, in d_out) + hb (bf16, aliases qb)
  ln_row<0><<<dim3(16384), blk, 0, stream>>>(r1, g1, be1, h, hb);
  // 6: ff1 = relu(hb@W1^T + b1) (M=16384, N=2048, K=1024)
  gemm_bt<EP_FF1><<<dim3(64, 8, 1), gblk, 0, stream>>>(
      hb, W1b, sP, 2048, 1024, 0, 0, 0, 0, b1, nullptr, 1.f);
  // 7: res2 = ff1@W2^T + b2 + h (M=16384, N=1024, K=2048)
  gemm_bt<EP_FF2><<<dim3(64, 4, 1), gblk, 0, stream>>>(
      sP, W2b, r1, 1024, 2048, 0, 0, 0, 0, b2, h, 1.f);
  // 8: LN2 -> out (overwrites h)
  ln_row<1><<<dim3(16384), blk, 0, stream>>>(r1, g2, be2, out, nullptr);
}

// Round 18
// 516.211 us; speedup vs baseline: 1.2138x; 1.0126x over previous
//
#include <hip/hip_runtime.h>
#include <hip/hip_bf16.h>

// ---------------------------------------------------------------------------
// MiniTransformer: B=8,S=2048,D=1024,H=2048, fp32 in/out, bf16 MFMA inside.
// GEMM R18: R15 ring (best, 493us) + XCD-aware block swizzle (T1).
// 256x256 tile, BK=64, 8 waves (2Mx4N), 2-dbuf LDS (128KB), 4 phases/K-tile,
// 2 barriers/K-tile (post-ph2 + boundary), counted vmcnt(4) ledger,
// compiler-counted lgkm waits, no setprio.
// T1: all GEMM grids are multiples of 8 blocks; linear block id remapped
// swz = (lin&7)*(nb/8) + (lin>>3) so each XCD's round-robin share becomes a
// CONTIGUOUS tile chunk -> one operand panel L2-resident per XCD.
// Pure tile permutation: zero correctness risk.
// (R13 32x32-MFMA, R14 16-wave, R16 128'-simple, R17 3-buf all regressed
// and are reverted; R15 drift schedule is the schedule-space optimum found.)
// LDS layout per half [128 rows][64k], slot XOR involution, 0 conflicts.
// Pipeline: cvt, QKV, scores, cvtW, softmax, PV, LN1, FF1, FF2, LN2.
// Scratch 234,881,024 B.
// ---------------------------------------------------------------------------

typedef __attribute__((ext_vector_type(4))) float  f32x4;
typedef __attribute__((ext_vector_type(8))) short  short8;
typedef __attribute__((ext_vector_type(4))) short  short4v;
typedef __attribute__((ext_vector_type(8))) __bf16 bf16x8;
typedef unsigned short ushort_t;

static __device__ __forceinline__ unsigned short f2bf(float f) {
  unsigned u = __builtin_bit_cast(unsigned, f);
  u += 0x7fffu + ((u >> 16) & 1u);  // RNE
  return (unsigned short)(u >> 16);
}
static __device__ __forceinline__ float bf2f(unsigned short u) {
  return __builtin_bit_cast(float, (unsigned)u << 16);
}

#define GLDS16(g, l)                                                        \
  __builtin_amdgcn_global_load_lds(                                         \
      (const __attribute__((address_space(1))) void*)(g),                   \
      (__attribute__((address_space(3))) void*)(l), 16, 0, 0)

// ---------------------------------------------------------------------------
__global__ __launch_bounds__(256) void cvt_f32_bf16(
    const float* __restrict__ in, ushort_t* __restrict__ out, long n) {
  long i = ((long)blockIdx.x * 256 + threadIdx.x) * 8;
  if (i >= n) return;
  f32x4 a = *(const f32x4*)(in + i);
  f32x4 b = *(const f32x4*)(in + i + 4);
  short8 t;
  t[0] = (short)f2bf(a.x); t[1] = (short)f2bf(a.y);
  t[2] = (short)f2bf(a.z); t[3] = (short)f2bf(a.w);
  t[4] = (short)f2bf(b.x); t[5] = (short)f2bf(b.y);
  t[6] = (short)f2bf(b.z); t[7] = (short)f2bf(b.w);
  *(short8*)(out + i) = t;
}

// ---------------------------------------------------------------------------
enum { EP_QKV = 0, EP_BF16 = 1, EP_PV = 2, EP_FF1 = 3, EP_FF2 = 4 };

constexpr long BSDc = 8L * 2048 * 1024;

template <int EPI>
__global__ __launch_bounds__(512, 2) void gemm_bt(
    const ushort_t* __restrict__ A, const ushort_t* __restrict__ B,
    void* __restrict__ C, int N, int K, long sA, long sB, long sC, long sRes,
    const float* __restrict__ bias, const float* __restrict__ res,
    float scale) {
  // [dbuf][half][128 rows x 64 k] per operand: 2*2*16KB*2 = 128KB.
  __shared__ __align__(16) ushort_t As[2][2][8192];
  __shared__ __align__(16) ushort_t Bs[2][2][8192];
  const int tid  = threadIdx.x;
  const int lane = tid & 63;
  const int w    = tid >> 6;        // 0..7
  const int wm   = w >> 2;          // 0..1 : wave row-half (128 rows)
  const int wn   = w & 3;           // 0..3 : wave col (64 cols)
  const int l15  = lane & 15;
  const int hi   = lane >> 4;       // 0..3 : 8-elem k-chunk

  // --- T1: XCD-aware bijective block swizzle (grid always multiple of 8) ---
  const long gx  = gridDim.x, gy = gridDim.y;
  const long nb  = gx * gy * (long)gridDim.z;
  const long lin = ((long)blockIdx.z * gy + blockIdx.y) * gx + blockIdx.x;
  const long cpx = nb >> 3;
  const long swz = (lin & 7) * cpx + (lin >> 3);
  const long bz  = swz / (gx * gy);
  const long rr  = swz - bz * gx * gy;
  const long byi = rr / gx;
  const long bxi = rr - byi * gx;

  const long m0  = bxi * 256;
  const long n0  = byi * 256;
  const ushort_t* Ab = A + bz * sA;
  const ushort_t* Bb = B + bz * sB;

  // Staging source (inverse of read-side XOR): thread handles phys chunks
  // tid and tid+512 of each 1024-chunk half. row = P>>3, slot = (P&7)^(row&7).
  const int srow = tid >> 3;
  const int sc   = (tid & 7) ^ (srow & 7);
  const long offA0 = (m0 + srow) * (long)K + sc * 8;
  const long offB0 = (n0 + srow) * (long)K + sc * 8;
  const int dst0 = w * 512;
  const int dst1 = 4096 + w * 512;

#define STAGE_A(t, h)                                                       \
  {                                                                         \
    const long o_ = (long)(t) * 64 + (long)(h) * 128 * K;                   \
    ushort_t* l_ = &As[(t) & 1][h][0];                                      \
    GLDS16(Ab + offA0 + o_, l_ + dst0);                                     \
    GLDS16(Ab + offA0 + 64 * (long)K + o_, l_ + dst1);                      \
  }
#define STAGE_B(t, h)                                                       \
  {                                                                         \
    const long o_ = (long)(t) * 64 + (long)(h) * 128 * K;                   \
    ushort_t* l_ = &Bs[(t) & 1][h][0];                                      \
    GLDS16(Bb + offB0 + o_, l_ + dst0);                                     \
    GLDS16(Bb + offB0 + 64 * (long)K + o_, l_ + dst1);                      \
  }

  // Read-side swizzled byte offsets (k-step 0 / 1), lane-constant.
  const int ab0 = l15 * 128 + ((hi) ^ (l15 & 7)) * 16;
  const int ab1 = l15 * 128 + ((4 + hi) ^ (l15 & 7)) * 16;

#define READ_A(ai)                                                          \
  _Pragma("unroll") for (int i = 0; i < 4; ++i) {                           \
    afr[i][0] = *(const short8*)(Ah + (ai) * 8192 + i * 2048 + ab0);        \
    afr[i][1] = *(const short8*)(Ah + (ai) * 8192 + i * 2048 + ab1);        \
  }
#define READ_B(bj)                                                          \
  _Pragma("unroll") for (int j = 0; j < 2; ++j) {                           \
    bfr[bj][j][0] = *(const short8*)(Bh + (bj) * 4096 + j * 2048 + ab0);    \
    bfr[bj][j][1] = *(const short8*)(Bh + (bj) * 4096 + j * 2048 + ab1);    \
  }
#define QMFMA(ib, jb, bsel)                                                 \
  _Pragma("unroll") for (int i = 0; i < 4; ++i)                             \
  _Pragma("unroll") for (int j = 0; j < 2; ++j)                             \
  _Pragma("unroll") for (int ks = 0; ks < 2; ++ks)                          \
    acc[(ib) + i][(jb) + j] = __builtin_amdgcn_mfma_f32_16x16x32_bf16(      \
        __builtin_bit_cast(bf16x8, afr[i][ks]),                             \
        __builtin_bit_cast(bf16x8, bfr[bsel][j][ks]),                       \
        acc[(ib) + i][(jb) + j], 0, 0, 0);

  f32x4 acc[8][4] = {};
  const int NT = K >> 6;  // K-tiles of 64 (16 or 32)

  // Prologue ring: (0).B0,B1,A0,A1,(1).B0,B1 = 12 loads; retire tile 0.
  STAGE_B(0, 0) STAGE_B(0, 1) STAGE_A(0, 0) STAGE_A(0, 1)
  STAGE_B(1, 0) STAGE_B(1, 1)
  asm volatile("s_waitcnt vmcnt(4)" ::: "memory");
  __builtin_amdgcn_sched_barrier(0);
  __builtin_amdgcn_s_barrier();
  __builtin_amdgcn_sched_barrier(0);

  for (int u = 0; u < NT; ++u) {
    const int d = u & 1;
    const char* Ah = (const char*)&As[d][wm][0];
    const char* Bh = (const char*)&Bs[d][wn >> 1][0] + (wn & 1) * 8192;
    short8 afr[4][2], bfr[2][2][2];
    // ---- phase 1: quadrant A0 x B0 (no bars: buf d confirmed at entry) ----
    READ_A(0)
    READ_B(0)
    if (u + 1 < NT) STAGE_A(u + 1, 0)
    QMFMA(0, 0, 0)
    // ---- phase 2: quadrant A0 x B1 ----
    READ_B(1)
    if (u + 1 < NT) STAGE_A(u + 1, 1)
    QMFMA(0, 2, 1)
    __builtin_amdgcn_s_barrier();  // all waves done reading B-halves of buf d
    // ---- phase 3: quadrant A1 x B1 (stage may overwrite buf d B0 now) ----
    READ_A(1)
    if (u + 2 < NT) STAGE_B(u + 2, 0)
    QMFMA(4, 2, 1)
    // ---- phase 4: quadrant A1 x B0 (all from regs) ----
    if (u + 2 < NT) STAGE_B(u + 2, 1)
    QMFMA(4, 0, 0)
    // ---- K-tile boundary: tile u+1 must be fully resident ----
    if (u + 1 < NT) {
      if (u + 2 < NT) {
        asm volatile("s_waitcnt vmcnt(4)" ::: "memory");
      } else {
        asm volatile("s_waitcnt vmcnt(0)" ::: "memory");
      }
      __builtin_amdgcn_sched_barrier(0);
      __builtin_amdgcn_s_barrier();
      __builtin_amdgcn_sched_barrier(0);
    }
  }
#undef STAGE_A
#undef STAGE_B
#undef READ_A
#undef READ_B
#undef QMFMA

  // Epilogue. C/D layout: col = lane&15, row = (lane>>4)*4 + reg.
  const int rb0 = hi << 2;
  const int cl  = l15;
#pragma unroll
  for (int i = 0; i < 8; ++i) {
#pragma unroll
    for (int j = 0; j < 4; ++j) {
      long gmb = m0 + wm * 128 + i * 16 + rb0;
      long gc  = n0 + wn * 64 + j * 16 + cl;
      if constexpr (EPI == EP_QKV) {
        long which = gc >> 10;  // 0=q, 1=k, 2=v (uniform per block)
        long col   = gc & 1023;
        if (which == 2) {
          long bb = gmb >> 11, s = gmb & 2047;
          short4v pk;
#pragma unroll
          for (int r = 0; r < 4; ++r) pk[r] = (short)f2bf(acc[i][j][r]);
          *(short4v*)((ushort_t*)C + 2 * BSDc + ((bb << 10) + col) * 2048 + s) =
              pk;
        } else {
#pragma unroll
          for (int r = 0; r < 4; ++r)
            ((ushort_t*)C)[which * BSDc + (gmb + r) * 1024 + col] =
                f2bf(acc[i][j][r]);
        }
      } else {
#pragma unroll
        for (int r = 0; r < 4; ++r) {
          long gm = gmb + r;
          float v = acc[i][j][r] * scale;
          if constexpr (EPI == EP_BF16) {
            ((ushort_t*)C)[bz * sC + gm * N + gc] = f2bf(v);
          } else if constexpr (EPI == EP_PV) {
            v += res[bz * sRes + gm * N + gc];
            ((float*)C)[bz * sC + gm * N + gc] = v;
          } else if constexpr (EPI == EP_FF1) {
            v += bias[gc];
            v = v > 0.f ? v : 0.f;
            ((ushort_t*)C)[gm * N + gc] = f2bf(v);
          } else {  // EP_FF2
            v += bias[gc] + res[gm * N + gc];
            ((float*)C)[gm * N + gc] = v;
          }
        }
      }
    }
  }
}

// ---------------------------------------------------------------------------
__global__ __launch_bounds__(256) void softmax_inplace(
    ushort_t* __restrict__ P) {
  __shared__ float rmax[4], rsum[4];
  const int tid   = threadIdx.x;
  const long base = (long)blockIdx.x * 2048;
  short8 sv = *(const short8*)(P + base + tid * 8);
  float v[8];
#pragma unroll
  for (int j = 0; j < 8; ++j) v[j] = bf2f((unsigned short)sv[j]);
  float mx = v[0];
#pragma unroll
  for (int j = 1; j < 8; ++j) mx = fmaxf(mx, v[j]);
#pragma unroll
  for (int off = 32; off; off >>= 1) mx = fmaxf(mx, __shfl_down(mx, off, 64));
  if ((tid & 63) == 0) rmax[tid >> 6] = mx;
  __syncthreads();
  mx = fmaxf(fmaxf(rmax[0], rmax[1]), fmaxf(rmax[2], rmax[3]));
  float s = 0.f;
#pragma unroll
  for (int j = 0; j < 8; ++j) {
    v[j] = __expf(v[j] - mx);
    s += v[j];
  }
#pragma unroll
  for (int off = 32; off; off >>= 1) s += __shfl_down(s, off, 64);
  if ((tid & 63) == 0) rsum[tid >> 6] = s;
  __syncthreads();
  s = (rsum[0] + rsum[1]) + (rsum[2] + rsum[3]);
  float inv = 1.f / s;
  short8 o;
#pragma unroll
  for (int j = 0; j < 8; ++j) o[j] = (short)f2bf(v[j] * inv);
  *(short8*)(P + base + tid * 8) = o;
}

// ---------------------------------------------------------------------------
template <int MODE>
__global__ __launch_bounds__(256) void ln_row(const float* __restrict__ X,
                                              const float* __restrict__ g,
                                              const float* __restrict__ be,
                                              float* __restrict__ Yf,
                                              ushort_t* __restrict__ Yb) {
  __shared__ float rs[4], rq[4];
  const int tid   = threadIdx.x;
  const long base = (long)blockIdx.x << 10;
  f32x4 v = *(const f32x4*)(X + base + tid * 4);
  float s = v.x + v.y + v.z + v.w;
  float q = v.x * v.x + v.y * v.y + v.z * v.z + v.w * v.w;
#pragma unroll
  for (int off = 32; off; off >>= 1) {
    s += __shfl_down(s, off, 64);
    q += __shfl_down(q, off, 64);
  }
  if ((tid & 63) == 0) {
    rs[tid >> 6] = s;
    rq[tid >> 6] = q;
  }
  __syncthreads();
  s = (rs[0] + rs[1]) + (rs[2] + rs[3]);
  q = (rq[0] + rq[1]) + (rq[2] + rq[3]);
  float mu   = s * (1.f / 1024.f);
  float var  = q * (1.f / 1024.f) - mu * mu;
  float rstd = rsqrtf(var + 1e-5f);
  int c    = tid * 4;
  f32x4 gg = *(const f32x4*)(g + c);
  f32x4 bb = *(const f32x4*)(be + c);
  f32x4 y;
  y.x = (v.x - mu) * rstd * gg.x + bb.x;
  y.y = (v.y - mu) * rstd * gg.y + bb.y;
  y.z = (v.z - mu) * rstd * gg.z + bb.z;
  y.w = (v.w - mu) * rstd * gg.w + bb.w;
  *(f32x4*)(Yf + base + c) = y;
  if constexpr (MODE == 0) {
    short4v ob;
    ob[0] = (short)f2bf(y.x);
    ob[1] = (short)f2bf(y.y);
    ob[2] = (short)f2bf(y.z);
    ob[3] = (short)f2bf(y.w);
    *(short4v*)(Yb + base + c) = ob;
  }
}

// ---------------------------------------------------------------------------
extern "C" void kernel_launch(void* const* d_in, const int* in_sizes, int n_in,
                              void* d_out, int out_size, void* d_ws,
                              size_t ws_size, hipStream_t stream) {
  const float* x   = (const float*)d_in[0];
  const float* Wq  = (const float*)d_in[1];
  const float* Wk  = (const float*)d_in[2];
  const float* Wv  = (const float*)d_in[3];
  const float* W1  = (const float*)d_in[4];
  const float* b1  = (const float*)d_in[5];
  const float* W2  = (const float*)d_in[6];
  const float* b2  = (const float*)d_in[7];
  const float* g1  = (const float*)d_in[8];
  const float* be1 = (const float*)d_in[9];
  const float* g2  = (const float*)d_in[10];
  const float* be2 = (const float*)d_in[11];
  float* out = (float*)d_out;

  constexpr long BSD = 8L * 2048 * 1024;
  constexpr long BSS = 8L * 2048 * 2048;
  constexpr long DD  = 1024L * 1024;
  constexpr long HD  = 2048L * 1024;

  // Scratch: qb | kb | vTb | sP | r1  = 234,881,024 bytes total.
  ushort_t* qb  = (ushort_t*)d_ws;
  ushort_t* kb  = qb + BSD;
  ushort_t* vTb = kb + BSD;
  ushort_t* sP  = vTb + BSD;
  float*    r1  = (float*)(sP + BSS);

  ushort_t* xb    = sP;              // dead before scores written
  ushort_t* Wqkvb = (ushort_t*)r1;   // dead before PV writes r1
  ushort_t* W1b   = kb;              // converted after scores GEMM
  ushort_t* W2b   = kb + HD;
  ushort_t* hb    = qb;
  float*    h     = out;             // d_out dead until LN2 rewrites it

  dim3 blk(256), gblk(512);
  const long SD = 2048L * 1024, SS = 2048L * 2048, DS = 1024L * 2048;

  // 0: conversions
  cvt_f32_bf16<<<dim3(8192), blk, 0, stream>>>(x, xb, BSD);
  cvt_f32_bf16<<<dim3(512), blk, 0, stream>>>(Wq, Wqkvb, DD);
  cvt_f32_bf16<<<dim3(512), blk, 0, stream>>>(Wk, Wqkvb + DD, DD);
  cvt_f32_bf16<<<dim3(512), blk, 0, stream>>>(Wv, Wqkvb + 2 * DD, DD);
  // 1: fused QKV projection (M=16384, N=3072, K=1024)
  gemm_bt<EP_QKV><<<dim3(64, 12, 1), gblk, 0, stream>>>(
      xb, Wqkvb, qb, 3072, 1024, 0, 0, 0, 0, nullptr, nullptr, 1.f);
  // 2: scores = q@k^T / 32 (per batch: M=N=2048, K=1024)
  gemm_bt<EP_BF16><<<dim3(8, 8, 8), gblk, 0, stream>>>(
      qb, kb, sP, 2048, 1024, SD, SD, SS, 0, nullptr, nullptr, 0.03125f);
  // 2b: FFN weights into kb region (kb dead now)
  cvt_f32_bf16<<<dim3(1024), blk, 0, stream>>>(W1, W1b, HD);
  cvt_f32_bf16<<<dim3(1024), blk, 0, stream>>>(W2, W2b, HD);
  // 3: softmax
  softmax_inplace<<<dim3(16384), blk, 0, stream>>>(sP);
  // 4: attn_out + x (per batch: M=2048, N=1024, K=2048)
  gemm_bt<EP_PV><<<dim3(8, 4, 8), gblk, 0, stream>>>(
      sP, vTb, r1, 1024, 2048, SS, DS, SD, SD, nullptr, x, 1.f);
  // 5: LN1 -> h (fp32, in d_out) + hb (bf16, aliases qb)
  ln_row<0><<<dim3(16384), blk, 0, stream>>>(r1, g1, be1, h, hb);
  // 6: ff1 = relu(hb@W1^T + b1) (M=16384, N=2048, K=1024)
  gemm_bt<EP_FF1><<<dim3(64, 8, 1), gblk, 0, stream>>>(
      hb, W1b, sP, 2048, 1024, 0, 0, 0, 0, b1, nullptr, 1.f);
  // 7: res2 = ff1@W2^T + b2 + h (M=16384, N=1024, K=2048)
  gemm_bt<EP_FF2><<<dim3(64, 4, 1), gblk, 0, stream>>>(
      sP, W2b, r1, 1024, 2048, 0, 0, 0, 0, b2, h, 1.f);
  // 8: LN2 -> out (overwrites h)
  ln_row<1><<<dim3(16384), blk, 0, stream>>>(r1, g2, be2, out, nullptr);
}

// Round 19
// 504.737 us; speedup vs baseline: 1.2414x; 1.0227x over previous
//
#include <hip/hip_runtime.h>
#include <hip/hip_bf16.h>

// ---------------------------------------------------------------------------
// MiniTransformer: B=8,S=2048,D=1024,H=2048, fp32 in/out, bf16 MFMA inside.
// GEMM R19: R15 ring (best, 493us) + 4x4 SUPERBLOCK remap (locality, no
// XCD-mapping assumption — R18's lin%8 swizzle tripled FETCH and is gone).
// Diagnosis: GEMMs are operand-STREAMING bound (~2.95 GB staged/iter at
// ~6 TB/s fabric = the 490us plateau). Old linearization: co-resident
// blocks share 1 B-panel but have 32 distinct A-panels (16.5MB >> 4MB L2).
// 4x4 superblocks: any 32 consecutive blocks span <=8 A + <=8 B panels
// (8MB) -> better L2 hit rate for ANY dispatch order correlated with lin.
// All grids divisible by 4x4: (64,12),(8,8,8),(8,4,8),(64,8),(64,4).
// Schedule unchanged from R15: 256x256, BK=64, 8 waves, 2-dbuf 128KB LDS,
// 2 barriers/K-tile, counted vmcnt(4), compiler lgkm waits, no setprio.
// LDS XOR chunk layout (0 conflicts). Pipeline: cvt, QKV, scores, cvtW,
// softmax, PV, LN1, FF1, FF2, LN2. Scratch 234,881,024 B.
// ---------------------------------------------------------------------------

typedef __attribute__((ext_vector_type(4))) float  f32x4;
typedef __attribute__((ext_vector_type(8))) short  short8;
typedef __attribute__((ext_vector_type(4))) short  short4v;
typedef __attribute__((ext_vector_type(8))) __bf16 bf16x8;
typedef unsigned short ushort_t;

static __device__ __forceinline__ unsigned short f2bf(float f) {
  unsigned u = __builtin_bit_cast(unsigned, f);
  u += 0x7fffu + ((u >> 16) & 1u);  // RNE
  return (unsigned short)(u >> 16);
}
static __device__ __forceinline__ float bf2f(unsigned short u) {
  return __builtin_bit_cast(float, (unsigned)u << 16);
}

#define GLDS16(g, l)                                                        \
  __builtin_amdgcn_global_load_lds(                                         \
      (const __attribute__((address_space(1))) void*)(g),                   \
      (__attribute__((address_space(3))) void*)(l), 16, 0, 0)

// ---------------------------------------------------------------------------
__global__ __launch_bounds__(256) void cvt_f32_bf16(
    const float* __restrict__ in, ushort_t* __restrict__ out, long n) {
  long i = ((long)blockIdx.x * 256 + threadIdx.x) * 8;
  if (i >= n) return;
  f32x4 a = *(const f32x4*)(in + i);
  f32x4 b = *(const f32x4*)(in + i + 4);
  short8 t;
  t[0] = (short)f2bf(a.x); t[1] = (short)f2bf(a.y);
  t[2] = (short)f2bf(a.z); t[3] = (short)f2bf(a.w);
  t[4] = (short)f2bf(b.x); t[5] = (short)f2bf(b.y);
  t[6] = (short)f2bf(b.z); t[7] = (short)f2bf(b.w);
  *(short8*)(out + i) = t;
}

// ---------------------------------------------------------------------------
enum { EP_QKV = 0, EP_BF16 = 1, EP_PV = 2, EP_FF1 = 3, EP_FF2 = 4 };

constexpr long BSDc = 8L * 2048 * 1024;

template <int EPI>
__global__ __launch_bounds__(512, 2) void gemm_bt(
    const ushort_t* __restrict__ A, const ushort_t* __restrict__ B,
    void* __restrict__ C, int N, int K, long sA, long sB, long sC, long sRes,
    const float* __restrict__ bias, const float* __restrict__ res,
    float scale) {
  // [dbuf][half][128 rows x 64 k] per operand: 2*2*16KB*2 = 128KB.
  __shared__ __align__(16) ushort_t As[2][2][8192];
  __shared__ __align__(16) ushort_t Bs[2][2][8192];
  const int tid  = threadIdx.x;
  const int lane = tid & 63;
  const int w    = tid >> 6;        // 0..7
  const int wm   = w >> 2;          // 0..1 : wave row-half (128 rows)
  const int wn   = w & 3;           // 0..3 : wave col (64 cols)
  const int l15  = lane & 15;
  const int hi   = lane >> 4;       // 0..3 : 8-elem k-chunk

  // --- 4x4 superblock remap (within the batch slice; gx%4==0, gy%4==0) ---
  const long gx  = gridDim.x;
  const long bz  = blockIdx.z;
  const long lin = (long)blockIdx.y * gx + blockIdx.x;
  const long sb  = lin >> 4, t4 = lin & 15;
  const long nsbx = gx >> 2;
  const long bxi = (sb % nsbx) * 4 + (t4 & 3);
  const long byi = (sb / nsbx) * 4 + (t4 >> 2);

  const long m0  = bxi * 256;
  const long n0  = byi * 256;
  const ushort_t* Ab = A + bz * sA;
  const ushort_t* Bb = B + bz * sB;

  // Staging source (inverse of read-side XOR): thread handles phys chunks
  // tid and tid+512 of each 1024-chunk half. row = P>>3, slot = (P&7)^(row&7).
  const int srow = tid >> 3;
  const int sc   = (tid & 7) ^ (srow & 7);
  const long offA0 = (m0 + srow) * (long)K + sc * 8;
  const long offB0 = (n0 + srow) * (long)K + sc * 8;
  const int dst0 = w * 512;
  const int dst1 = 4096 + w * 512;

#define STAGE_A(t, h)                                                       \
  {                                                                         \
    const long o_ = (long)(t) * 64 + (long)(h) * 128 * K;                   \
    ushort_t* l_ = &As[(t) & 1][h][0];                                      \
    GLDS16(Ab + offA0 + o_, l_ + dst0);                                     \
    GLDS16(Ab + offA0 + 64 * (long)K + o_, l_ + dst1);                      \
  }
#define STAGE_B(t, h)                                                       \
  {                                                                         \
    const long o_ = (long)(t) * 64 + (long)(h) * 128 * K;                   \
    ushort_t* l_ = &Bs[(t) & 1][h][0];                                      \
    GLDS16(Bb + offB0 + o_, l_ + dst0);                                     \
    GLDS16(Bb + offB0 + 64 * (long)K + o_, l_ + dst1);                      \
  }

  // Read-side swizzled byte offsets (k-step 0 / 1), lane-constant.
  const int ab0 = l15 * 128 + ((hi) ^ (l15 & 7)) * 16;
  const int ab1 = l15 * 128 + ((4 + hi) ^ (l15 & 7)) * 16;

#define READ_A(ai)                                                          \
  _Pragma("unroll") for (int i = 0; i < 4; ++i) {                           \
    afr[i][0] = *(const short8*)(Ah + (ai) * 8192 + i * 2048 + ab0);        \
    afr[i][1] = *(const short8*)(Ah + (ai) * 8192 + i * 2048 + ab1);        \
  }
#define READ_B(bj)                                                          \
  _Pragma("unroll") for (int j = 0; j < 2; ++j) {                           \
    bfr[bj][j][0] = *(const short8*)(Bh + (bj) * 4096 + j * 2048 + ab0);    \
    bfr[bj][j][1] = *(const short8*)(Bh + (bj) * 4096 + j * 2048 + ab1);    \
  }
#define QMFMA(ib, jb, bsel)                                                 \
  _Pragma("unroll") for (int i = 0; i < 4; ++i)                             \
  _Pragma("unroll") for (int j = 0; j < 2; ++j)                             \
  _Pragma("unroll") for (int ks = 0; ks < 2; ++ks)                          \
    acc[(ib) + i][(jb) + j] = __builtin_amdgcn_mfma_f32_16x16x32_bf16(      \
        __builtin_bit_cast(bf16x8, afr[i][ks]),                             \
        __builtin_bit_cast(bf16x8, bfr[bsel][j][ks]),                       \
        acc[(ib) + i][(jb) + j], 0, 0, 0);

  f32x4 acc[8][4] = {};
  const int NT = K >> 6;  // K-tiles of 64 (16 or 32)

  // Prologue ring: (0).B0,B1,A0,A1,(1).B0,B1 = 12 loads; retire tile 0.
  STAGE_B(0, 0) STAGE_B(0, 1) STAGE_A(0, 0) STAGE_A(0, 1)
  STAGE_B(1, 0) STAGE_B(1, 1)
  asm volatile("s_waitcnt vmcnt(4)" ::: "memory");
  __builtin_amdgcn_sched_barrier(0);
  __builtin_amdgcn_s_barrier();
  __builtin_amdgcn_sched_barrier(0);

  for (int u = 0; u < NT; ++u) {
    const int d = u & 1;
    const char* Ah = (const char*)&As[d][wm][0];
    const char* Bh = (const char*)&Bs[d][wn >> 1][0] + (wn & 1) * 8192;
    short8 afr[4][2], bfr[2][2][2];
    // ---- phase 1: quadrant A0 x B0 (no bars: buf d confirmed at entry) ----
    READ_A(0)
    READ_B(0)
    if (u + 1 < NT) STAGE_A(u + 1, 0)
    QMFMA(0, 0, 0)
    // ---- phase 2: quadrant A0 x B1 ----
    READ_B(1)
    if (u + 1 < NT) STAGE_A(u + 1, 1)
    QMFMA(0, 2, 1)
    __builtin_amdgcn_s_barrier();  // all waves done reading B-halves of buf d
    // ---- phase 3: quadrant A1 x B1 (stage may overwrite buf d B0 now) ----
    READ_A(1)
    if (u + 2 < NT) STAGE_B(u + 2, 0)
    QMFMA(4, 2, 1)
    // ---- phase 4: quadrant A1 x B0 (all from regs) ----
    if (u + 2 < NT) STAGE_B(u + 2, 1)
    QMFMA(4, 0, 0)
    // ---- K-tile boundary: tile u+1 must be fully resident ----
    if (u + 1 < NT) {
      if (u + 2 < NT) {
        asm volatile("s_waitcnt vmcnt(4)" ::: "memory");
      } else {
        asm volatile("s_waitcnt vmcnt(0)" ::: "memory");
      }
      __builtin_amdgcn_sched_barrier(0);
      __builtin_amdgcn_s_barrier();
      __builtin_amdgcn_sched_barrier(0);
    }
  }
#undef STAGE_A
#undef STAGE_B
#undef READ_A
#undef READ_B
#undef QMFMA

  // Epilogue. C/D layout: col = lane&15, row = (lane>>4)*4 + reg.
  const int rb0 = hi << 2;
  const int cl  = l15;
#pragma unroll
  for (int i = 0; i < 8; ++i) {
#pragma unroll
    for (int j = 0; j < 4; ++j) {
      long gmb = m0 + wm * 128 + i * 16 + rb0;
      long gc  = n0 + wn * 64 + j * 16 + cl;
      if constexpr (EPI == EP_QKV) {
        long which = gc >> 10;  // 0=q, 1=k, 2=v (uniform per block)
        long col   = gc & 1023;
        if (which == 2) {
          long bb = gmb >> 11, s = gmb & 2047;
          short4v pk;
#pragma unroll
          for (int r = 0; r < 4; ++r) pk[r] = (short)f2bf(acc[i][j][r]);
          *(short4v*)((ushort_t*)C + 2 * BSDc + ((bb << 10) + col) * 2048 + s) =
              pk;
        } else {
#pragma unroll
          for (int r = 0; r < 4; ++r)
            ((ushort_t*)C)[which * BSDc + (gmb + r) * 1024 + col] =
                f2bf(acc[i][j][r]);
        }
      } else {
#pragma unroll
        for (int r = 0; r < 4; ++r) {
          long gm = gmb + r;
          float v = acc[i][j][r] * scale;
          if constexpr (EPI == EP_BF16) {
            ((ushort_t*)C)[bz * sC + gm * N + gc] = f2bf(v);
          } else if constexpr (EPI == EP_PV) {
            v += res[bz * sRes + gm * N + gc];
            ((float*)C)[bz * sC + gm * N + gc] = v;
          } else if constexpr (EPI == EP_FF1) {
            v += bias[gc];
            v = v > 0.f ? v : 0.f;
            ((ushort_t*)C)[gm * N + gc] = f2bf(v);
          } else {  // EP_FF2
            v += bias[gc] + res[gm * N + gc];
            ((float*)C)[gm * N + gc] = v;
          }
        }
      }
    }
  }
}

// ---------------------------------------------------------------------------
__global__ __launch_bounds__(256) void softmax_inplace(
    ushort_t* __restrict__ P) {
  __shared__ float rmax[4], rsum[4];
  const int tid   = threadIdx.x;
  const long base = (long)blockIdx.x * 2048;
  short8 sv = *(const short8*)(P + base + tid * 8);
  float v[8];
#pragma unroll
  for (int j = 0; j < 8; ++j) v[j] = bf2f((unsigned short)sv[j]);
  float mx = v[0];
#pragma unroll
  for (int j = 1; j < 8; ++j) mx = fmaxf(mx, v[j]);
#pragma unroll
  for (int off = 32; off; off >>= 1) mx = fmaxf(mx, __shfl_down(mx, off, 64));
  if ((tid & 63) == 0) rmax[tid >> 6] = mx;
  __syncthreads();
  mx = fmaxf(fmaxf(rmax[0], rmax[1]), fmaxf(rmax[2], rmax[3]));
  float s = 0.f;
#pragma unroll
  for (int j = 0; j < 8; ++j) {
    v[j] = __expf(v[j] - mx);
    s += v[j];
  }
#pragma unroll
  for (int off = 32; off; off >>= 1) s += __shfl_down(s, off, 64);
  if ((tid & 63) == 0) rsum[tid >> 6] = s;
  __syncthreads();
  s = (rsum[0] + rsum[1]) + (rsum[2] + rsum[3]);
  float inv = 1.f / s;
  short8 o;
#pragma unroll
  for (int j = 0; j < 8; ++j) o[j] = (short)f2bf(v[j] * inv);
  *(short8*)(P + base + tid * 8) = o;
}

// ---------------------------------------------------------------------------
template <int MODE>
__global__ __launch_bounds__(256) void ln_row(const float* __restrict__ X,
                                              const float* __restrict__ g,
                                              const float* __restrict__ be,
                                              float* __restrict__ Yf,
                                              ushort_t* __restrict__ Yb) {
  __shared__ float rs[4], rq[4];
  const int tid   = threadIdx.x;
  const long base = (long)blockIdx.x << 10;
  f32x4 v = *(const f32x4*)(X + base + tid * 4);
  float s = v.x + v.y + v.z + v.w;
  float q = v.x * v.x + v.y * v.y + v.z * v.z + v.w * v.w;
#pragma unroll
  for (int off = 32; off; off >>= 1) {
    s += __shfl_down(s, off, 64);
    q += __shfl_down(q, off, 64);
  }
  if ((tid & 63) == 0) {
    rs[tid >> 6] = s;
    rq[tid >> 6] = q;
  }
  __syncthreads();
  s = (rs[0] + rs[1]) + (rs[2] + rs[3]);
  q = (rq[0] + rq[1]) + (rq[2] + rq[3]);
  float mu   = s * (1.f / 1024.f);
  float var  = q * (1.f / 1024.f) - mu * mu;
  float rstd = rsqrtf(var + 1e-5f);
  int c    = tid * 4;
  f32x4 gg = *(const f32x4*)(g + c);
  f32x4 bb = *(const f32x4*)(be + c);
  f32x4 y;
  y.x = (v.x - mu) * rstd * gg.x + bb.x;
  y.y = (v.y - mu) * rstd * gg.y + bb.y;
  y.z = (v.z - mu) * rstd * gg.z + bb.z;
  y.w = (v.w - mu) * rstd * gg.w + bb.w;
  *(f32x4*)(Yf + base + c) = y;
  if constexpr (MODE == 0) {
    short4v ob;
    ob[0] = (short)f2bf(y.x);
    ob[1] = (short)f2bf(y.y);
    ob[2] = (short)f2bf(y.z);
    ob[3] = (short)f2bf(y.w);
    *(short4v*)(Yb + base + c) = ob;
  }
}

// ---------------------------------------------------------------------------
extern "C" void kernel_launch(void* const* d_in, const int* in_sizes, int n_in,
                              void* d_out, int out_size, void* d_ws,
                              size_t ws_size, hipStream_t stream) {
  const float* x   = (const float*)d_in[0];
  const float* Wq  = (const float*)d_in[1];
  const float* Wk  = (const float*)d_in[2];
  const float* Wv  = (const float*)d_in[3];
  const float* W1  = (const float*)d_in[4];
  const float* b1  = (const float*)d_in[5];
  const float* W2  = (const float*)d_in[6];
  const float* b2  = (const float*)d_in[7];
  const float* g1  = (const float*)d_in[8];
  const float* be1 = (const float*)d_in[9];
  const float* g2  = (const float*)d_in[10];
  const float* be2 = (const float*)d_in[11];
  float* out = (float*)d_out;

  constexpr long BSD = 8L * 2048 * 1024;
  constexpr long BSS = 8L * 2048 * 2048;
  constexpr long DD  = 1024L * 1024;
  constexpr long HD  = 2048L * 1024;

  // Scratch: qb | kb | vTb | sP | r1  = 234,881,024 bytes total.
  ushort_t* qb  = (ushort_t*)d_ws;
  ushort_t* kb  = qb + BSD;
  ushort_t* vTb = kb + BSD;
  ushort_t* sP  = vTb + BSD;
  float*    r1  = (float*)(sP + BSS);

  ushort_t* xb    = sP;              // dead before scores written
  ushort_t* Wqkvb = (ushort_t*)r1;   // dead before PV writes r1
  ushort_t* W1b   = kb;              // converted after scores GEMM
  ushort_t* W2b   = kb + HD;
  ushort_t* hb    = qb;
  float*    h     = out;             // d_out dead until LN2 rewrites it

  dim3 blk(256), gblk(512);
  const long SD = 2048L * 1024, SS = 2048L * 2048, DS = 1024L * 2048;

  // 0: conversions
  cvt_f32_bf16<<<dim3(8192), blk, 0, stream>>>(x, xb, BSD);
  cvt_f32_bf16<<<dim3(512), blk, 0, stream>>>(Wq, Wqkvb, DD);
  cvt_f32_bf16<<<dim3(512), blk, 0, stream>>>(Wk, Wqkvb + DD, DD);
  cvt_f32_bf16<<<dim3(512), blk, 0, stream>>>(Wv, Wqkvb + 2 * DD, DD);
  // 1: fused QKV projection (M=16384, N=3072, K=1024)
  gemm_bt<EP_QKV><<<dim3(64, 12, 1), gblk, 0, stream>>>(
      xb, Wqkvb, qb, 3072, 1024, 0, 0, 0, 0, nullptr, nullptr, 1.f);
  // 2: scores = q@k^T / 32 (per batch: M=N=2048, K=1024)
  gemm_bt<EP_BF16><<<dim3(8, 8, 8), gblk, 0, stream>>>(
      qb, kb, sP, 2048, 1024, SD, SD, SS, 0, nullptr, nullptr, 0.03125f);
  // 2b: FFN weights into kb region (kb dead now)
  cvt_f32_bf16<<<dim3(1024), blk, 0, stream>>>(W1, W1b, HD);
  cvt_f32_bf16<<<dim3(1024), blk, 0, stream>>>(W2, W2b, HD);
  // 3: softmax
  softmax_inplace<<<dim3(16384), blk, 0, stream>>>(sP);
  // 4: attn_out + x (per batch: M=2048, N=1024, K=2048)
  gemm_bt<EP_PV><<<dim3(8, 4, 8), gblk, 0, stream>>>(
      sP, vTb, r1, 1024, 2048, SS, DS, SD, SD, nullptr, x, 1.f);
  // 5: LN1 -> h (fp32, in d_out) + hb (bf16, aliases qb)
  ln_row<0><<<dim3(16384), blk, 0, stream>>>(r1, g1, be1, h, hb);
  // 6: ff1 = relu(hb@W1^T + b1) (M=16384, N=2048, K=1024)
  gemm_bt<EP_FF1><<<dim3(64, 8, 1), gblk, 0, stream>>>(
      hb, W1b, sP, 2048, 1024, 0, 0, 0, 0, b1, nullptr, 1.f);
  // 7: res2 = ff1@W2^T + b2 + h (M=16384, N=1024, K=2048)
  gemm_bt<EP_FF2><<<dim3(64, 4, 1), gblk, 0, stream>>>(
      sP, W2b, r1, 1024, 2048, 0, 0, 0, 0, b2, h, 1.f);
  // 8: LN2 -> out (overwrites h)
  ln_row<1><<<dim3(16384), blk, 0, stream>>>(r1, g2, be2, out, nullptr);
}

// Round 20
// 495.605 us; speedup vs baseline: 1.2643x; 1.0184x over previous
//
#include <hip/hip_runtime.h>
#include <hip/hip_bf16.h>

// ---------------------------------------------------------------------------
// MiniTransformer: B=8,S=2048,D=1024,H=2048, fp32 in/out, bf16 MFMA inside.
// FINAL (R20 = R15 exact, session best 493us).
// GEMM: 256x256 tile, BK=64, 8 waves (2Mx4N), 2-dbuf LDS (128KB),
// 4 phases/K-tile, 2 barriers/K-tile (post-ph2 + boundary), counted
// vmcnt(4) ledger (never 0 in steady state), compiler-counted lgkm waits,
// natural block linearization (both locality remaps R18/R19 raised FETCH
// and were reverted; time is FETCH-insensitive -> not cache-bound).
// Session ledger: 967->741->647->573->548->524->516->503->493us.
// Known gap: MfmaUtil 33% vs m201's 62% -- the fine-grained per-phase
// interleave requires the full HK/m201 co-design (subtiled layout +
// derived waits); isolated ports all regressed (R7,R9,R13,R14,R16,R17).
// LDS layout per half [128 rows][64k], slot XOR involution, 0 conflicts.
// Pipeline: cvt, QKV(fused,vT), scores, cvtW, softmax, PV+res, LN1,
// FF1(bias+relu), FF2(bias+res), LN2. Scratch 234,881,024 B.
// ---------------------------------------------------------------------------

typedef __attribute__((ext_vector_type(4))) float  f32x4;
typedef __attribute__((ext_vector_type(8))) short  short8;
typedef __attribute__((ext_vector_type(4))) short  short4v;
typedef __attribute__((ext_vector_type(8))) __bf16 bf16x8;
typedef unsigned short ushort_t;

static __device__ __forceinline__ unsigned short f2bf(float f) {
  unsigned u = __builtin_bit_cast(unsigned, f);
  u += 0x7fffu + ((u >> 16) & 1u);  // RNE
  return (unsigned short)(u >> 16);
}
static __device__ __forceinline__ float bf2f(unsigned short u) {
  return __builtin_bit_cast(float, (unsigned)u << 16);
}

#define GLDS16(g, l)                                                        \
  __builtin_amdgcn_global_load_lds(                                         \
      (const __attribute__((address_space(1))) void*)(g),                   \
      (__attribute__((address_space(3))) void*)(l), 16, 0, 0)

// ---------------------------------------------------------------------------
__global__ __launch_bounds__(256) void cvt_f32_bf16(
    const float* __restrict__ in, ushort_t* __restrict__ out, long n) {
  long i = ((long)blockIdx.x * 256 + threadIdx.x) * 8;
  if (i >= n) return;
  f32x4 a = *(const f32x4*)(in + i);
  f32x4 b = *(const f32x4*)(in + i + 4);
  short8 t;
  t[0] = (short)f2bf(a.x); t[1] = (short)f2bf(a.y);
  t[2] = (short)f2bf(a.z); t[3] = (short)f2bf(a.w);
  t[4] = (short)f2bf(b.x); t[5] = (short)f2bf(b.y);
  t[6] = (short)f2bf(b.z); t[7] = (short)f2bf(b.w);
  *(short8*)(out + i) = t;
}

// ---------------------------------------------------------------------------
enum { EP_QKV = 0, EP_BF16 = 1, EP_PV = 2, EP_FF1 = 3, EP_FF2 = 4 };

constexpr long BSDc = 8L * 2048 * 1024;

template <int EPI>
__global__ __launch_bounds__(512, 2) void gemm_bt(
    const ushort_t* __restrict__ A, const ushort_t* __restrict__ B,
    void* __restrict__ C, int N, int K, long sA, long sB, long sC, long sRes,
    const float* __restrict__ bias, const float* __restrict__ res,
    float scale) {
  // [dbuf][half][128 rows x 64 k] per operand: 2*2*16KB*2 = 128KB.
  __shared__ __align__(16) ushort_t As[2][2][8192];
  __shared__ __align__(16) ushort_t Bs[2][2][8192];
  const int tid  = threadIdx.x;
  const int lane = tid & 63;
  const int w    = tid >> 6;        // 0..7
  const int wm   = w >> 2;          // 0..1 : wave row-half (128 rows)
  const int wn   = w & 3;           // 0..3 : wave col (64 cols)
  const int l15  = lane & 15;
  const int hi   = lane >> 4;       // 0..3 : 8-elem k-chunk
  const long bz  = blockIdx.z;
  const long m0  = (long)blockIdx.x * 256;
  const long n0  = (long)blockIdx.y * 256;
  const ushort_t* Ab = A + bz * sA;
  const ushort_t* Bb = B + bz * sB;

  // Staging source (inverse of read-side XOR): thread handles phys chunks
  // tid and tid+512 of each 1024-chunk half. row = P>>3, slot = (P&7)^(row&7).
  const int srow = tid >> 3;
  const int sc   = (tid & 7) ^ (srow & 7);
  const long offA0 = (m0 + srow) * (long)K + sc * 8;
  const long offB0 = (n0 + srow) * (long)K + sc * 8;
  const int dst0 = w * 512;
  const int dst1 = 4096 + w * 512;

#define STAGE_A(t, h)                                                       \
  {                                                                         \
    const long o_ = (long)(t) * 64 + (long)(h) * 128 * K;                   \
    ushort_t* l_ = &As[(t) & 1][h][0];                                      \
    GLDS16(Ab + offA0 + o_, l_ + dst0);                                     \
    GLDS16(Ab + offA0 + 64 * (long)K + o_, l_ + dst1);                      \
  }
#define STAGE_B(t, h)                                                       \
  {                                                                         \
    const long o_ = (long)(t) * 64 + (long)(h) * 128 * K;                   \
    ushort_t* l_ = &Bs[(t) & 1][h][0];                                      \
    GLDS16(Bb + offB0 + o_, l_ + dst0);                                     \
    GLDS16(Bb + offB0 + 64 * (long)K + o_, l_ + dst1);                      \
  }

  // Read-side swizzled byte offsets (k-step 0 / 1), lane-constant.
  const int ab0 = l15 * 128 + ((hi) ^ (l15 & 7)) * 16;
  const int ab1 = l15 * 128 + ((4 + hi) ^ (l15 & 7)) * 16;

#define READ_A(ai)                                                          \
  _Pragma("unroll") for (int i = 0; i < 4; ++i) {                           \
    afr[i][0] = *(const short8*)(Ah + (ai) * 8192 + i * 2048 + ab0);        \
    afr[i][1] = *(const short8*)(Ah + (ai) * 8192 + i * 2048 + ab1);        \
  }
#define READ_B(bj)                                                          \
  _Pragma("unroll") for (int j = 0; j < 2; ++j) {                           \
    bfr[bj][j][0] = *(const short8*)(Bh + (bj) * 4096 + j * 2048 + ab0);    \
    bfr[bj][j][1] = *(const short8*)(Bh + (bj) * 4096 + j * 2048 + ab1);    \
  }
#define QMFMA(ib, jb, bsel)                                                 \
  _Pragma("unroll") for (int i = 0; i < 4; ++i)                             \
  _Pragma("unroll") for (int j = 0; j < 2; ++j)                             \
  _Pragma("unroll") for (int ks = 0; ks < 2; ++ks)                          \
    acc[(ib) + i][(jb) + j] = __builtin_amdgcn_mfma_f32_16x16x32_bf16(      \
        __builtin_bit_cast(bf16x8, afr[i][ks]),                             \
        __builtin_bit_cast(bf16x8, bfr[bsel][j][ks]),                       \
        acc[(ib) + i][(jb) + j], 0, 0, 0);

  f32x4 acc[8][4] = {};
  const int NT = K >> 6;  // K-tiles of 64 (16 or 32)

  // Prologue ring: (0).B0,B1,A0,A1,(1).B0,B1 = 12 loads; retire tile 0.
  STAGE_B(0, 0) STAGE_B(0, 1) STAGE_A(0, 0) STAGE_A(0, 1)
  STAGE_B(1, 0) STAGE_B(1, 1)
  asm volatile("s_waitcnt vmcnt(4)" ::: "memory");
  __builtin_amdgcn_sched_barrier(0);
  __builtin_amdgcn_s_barrier();
  __builtin_amdgcn_sched_barrier(0);

  for (int u = 0; u < NT; ++u) {
    const int d = u & 1;
    const char* Ah = (const char*)&As[d][wm][0];
    const char* Bh = (const char*)&Bs[d][wn >> 1][0] + (wn & 1) * 8192;
    short8 afr[4][2], bfr[2][2][2];
    // ---- phase 1: quadrant A0 x B0 (no bars: buf d confirmed at entry) ----
    READ_A(0)
    READ_B(0)
    if (u + 1 < NT) STAGE_A(u + 1, 0)
    QMFMA(0, 0, 0)
    // ---- phase 2: quadrant A0 x B1 ----
    READ_B(1)
    if (u + 1 < NT) STAGE_A(u + 1, 1)
    QMFMA(0, 2, 1)
    __builtin_amdgcn_s_barrier();  // all waves done reading B-halves of buf d
    // ---- phase 3: quadrant A1 x B1 (stage may overwrite buf d B0 now) ----
    READ_A(1)
    if (u + 2 < NT) STAGE_B(u + 2, 0)
    QMFMA(4, 2, 1)
    // ---- phase 4: quadrant A1 x B0 (all from regs) ----
    if (u + 2 < NT) STAGE_B(u + 2, 1)
    QMFMA(4, 0, 0)
    // ---- K-tile boundary: tile u+1 must be fully resident ----
    if (u + 1 < NT) {
      if (u + 2 < NT) {
        asm volatile("s_waitcnt vmcnt(4)" ::: "memory");
      } else {
        asm volatile("s_waitcnt vmcnt(0)" ::: "memory");
      }
      __builtin_amdgcn_sched_barrier(0);
      __builtin_amdgcn_s_barrier();
      __builtin_amdgcn_sched_barrier(0);
    }
  }
#undef STAGE_A
#undef STAGE_B
#undef READ_A
#undef READ_B
#undef QMFMA

  // Epilogue. C/D layout: col = lane&15, row = (lane>>4)*4 + reg.
  const int rb0 = hi << 2;
  const int cl  = l15;
#pragma unroll
  for (int i = 0; i < 8; ++i) {
#pragma unroll
    for (int j = 0; j < 4; ++j) {
      long gmb = m0 + wm * 128 + i * 16 + rb0;
      long gc  = n0 + wn * 64 + j * 16 + cl;
      if constexpr (EPI == EP_QKV) {
        long which = gc >> 10;  // 0=q, 1=k, 2=v (uniform per block)
        long col   = gc & 1023;
        if (which == 2) {
          long bb = gmb >> 11, s = gmb & 2047;
          short4v pk;
#pragma unroll
          for (int r = 0; r < 4; ++r) pk[r] = (short)f2bf(acc[i][j][r]);
          *(short4v*)((ushort_t*)C + 2 * BSDc + ((bb << 10) + col) * 2048 + s) =
              pk;
        } else {
#pragma unroll
          for (int r = 0; r < 4; ++r)
            ((ushort_t*)C)[which * BSDc + (gmb + r) * 1024 + col] =
                f2bf(acc[i][j][r]);
        }
      } else {
#pragma unroll
        for (int r = 0; r < 4; ++r) {
          long gm = gmb + r;
          float v = acc[i][j][r] * scale;
          if constexpr (EPI == EP_BF16) {
            ((ushort_t*)C)[bz * sC + gm * N + gc] = f2bf(v);
          } else if constexpr (EPI == EP_PV) {
            v += res[bz * sRes + gm * N + gc];
            ((float*)C)[bz * sC + gm * N + gc] = v;
          } else if constexpr (EPI == EP_FF1) {
            v += bias[gc];
            v = v > 0.f ? v : 0.f;
            ((ushort_t*)C)[gm * N + gc] = f2bf(v);
          } else {  // EP_FF2
            v += bias[gc] + res[gm * N + gc];
            ((float*)C)[gm * N + gc] = v;
          }
        }
      }
    }
  }
}

// ---------------------------------------------------------------------------
__global__ __launch_bounds__(256) void softmax_inplace(
    ushort_t* __restrict__ P) {
  __shared__ float rmax[4], rsum[4];
  const int tid   = threadIdx.x;
  const long base = (long)blockIdx.x * 2048;
  short8 sv = *(const short8*)(P + base + tid * 8);
  float v[8];
#pragma unroll
  for (int j = 0; j < 8; ++j) v[j] = bf2f((unsigned short)sv[j]);
  float mx = v[0];
#pragma unroll
  for (int j = 1; j < 8; ++j) mx = fmaxf(mx, v[j]);
#pragma unroll
  for (int off = 32; off; off >>= 1) mx = fmaxf(mx, __shfl_down(mx, off, 64));
  if ((tid & 63) == 0) rmax[tid >> 6] = mx;
  __syncthreads();
  mx = fmaxf(fmaxf(rmax[0], rmax[1]), fmaxf(rmax[2], rmax[3]));
  float s = 0.f;
#pragma unroll
  for (int j = 0; j < 8; ++j) {
    v[j] = __expf(v[j] - mx);
    s += v[j];
  }
#pragma unroll
  for (int off = 32; off; off >>= 1) s += __shfl_down(s, off, 64);
  if ((tid & 63) == 0) rsum[tid >> 6] = s;
  __syncthreads();
  s = (rsum[0] + rsum[1]) + (rsum[2] + rsum[3]);
  float inv = 1.f / s;
  short8 o;
#pragma unroll
  for (int j = 0; j < 8; ++j) o[j] = (short)f2bf(v[j] * inv);
  *(short8*)(P + base + tid * 8) = o;
}

// ---------------------------------------------------------------------------
template <int MODE>
__global__ __launch_bounds__(256) void ln_row(const float* __restrict__ X,
                                              const float* __restrict__ g,
                                              const float* __restrict__ be,
                                              float* __restrict__ Yf,
                                              ushort_t* __restrict__ Yb) {
  __shared__ float rs[4], rq[4];
  const int tid   = threadIdx.x;
  const long base = (long)blockIdx.x << 10;
  f32x4 v = *(const f32x4*)(X + base + tid * 4);
  float s = v.x + v.y + v.z + v.w;
  float q = v.x * v.x + v.y * v.y + v.z * v.z + v.w * v.w;
#pragma unroll
  for (int off = 32; off; off >>= 1) {
    s += __shfl_down(s, off, 64);
    q += __shfl_down(q, off, 64);
  }
  if ((tid & 63) == 0) {
    rs[tid >> 6] = s;
    rq[tid >> 6] = q;
  }
  __syncthreads();
  s = (rs[0] + rs[1]) + (rs[2] + rs[3]);
  q = (rq[0] + rq[1]) + (rq[2] + rq[3]);
  float mu   = s * (1.f / 1024.f);
  float var  = q * (1.f / 1024.f) - mu * mu;
  float rstd = rsqrtf(var + 1e-5f);
  int c    = tid * 4;
  f32x4 gg = *(const f32x4*)(g + c);
  f32x4 bb = *(const f32x4*)(be + c);
  f32x4 y;
  y.x = (v.x - mu) * rstd * gg.x + bb.x;
  y.y = (v.y - mu) * rstd * gg.y + bb.y;
  y.z = (v.z - mu) * rstd * gg.z + bb.z;
  y.w = (v.w - mu) * rstd * gg.w + bb.w;
  *(f32x4*)(Yf + base + c) = y;
  if constexpr (MODE == 0) {
    short4v ob;
    ob[0] = (short)f2bf(y.x);
    ob[1] = (short)f2bf(y.y);
    ob[2] = (short)f2bf(y.z);
    ob[3] = (short)f2bf(y.w);
    *(short4v*)(Yb + base + c) = ob;
  }
}

// ---------------------------------------------------------------------------
extern "C" void kernel_launch(void* const* d_in, const int* in_sizes, int n_in,
                              void* d_out, int out_size, void* d_ws,
                              size_t ws_size, hipStream_t stream) {
  const float* x   = (const float*)d_in[0];
  const float* Wq  = (const float*)d_in[1];
  const float* Wk  = (const float*)d_in[2];
  const float* Wv  = (const float*)d_in[3];
  const float* W1  = (const float*)d_in[4];
  const float* b1  = (const float*)d_in[5];
  const float* W2  = (const float*)d_in[6];
  const float* b2  = (const float*)d_in[7];
  const float* g1  = (const float*)d_in[8];
  const float* be1 = (const float*)d_in[9];
  const float* g2  = (const float*)d_in[10];
  const float* be2 = (const float*)d_in[11];
  float* out = (float*)d_out;

  constexpr long BSD = 8L * 2048 * 1024;
  constexpr long BSS = 8L * 2048 * 2048;
  constexpr long DD  = 1024L * 1024;
  constexpr long HD  = 2048L * 1024;

  // Scratch: qb | kb | vTb | sP | r1  = 234,881,024 bytes total.
  ushort_t* qb  = (ushort_t*)d_ws;
  ushort_t* kb  = qb + BSD;
  ushort_t* vTb = kb + BSD;
  ushort_t* sP  = vTb + BSD;
  float*    r1  = (float*)(sP + BSS);

  ushort_t* xb    = sP;              // dead before scores written
  ushort_t* Wqkvb = (ushort_t*)r1;   // dead before PV writes r1
  ushort_t* W1b   = kb;              // converted after scores GEMM
  ushort_t* W2b   = kb + HD;
  ushort_t* hb    = qb;
  float*    h     = out;             // d_out dead until LN2 rewrites it

  dim3 blk(256), gblk(512);
  const long SD = 2048L * 1024, SS = 2048L * 2048, DS = 1024L * 2048;

  // 0: conversions
  cvt_f32_bf16<<<dim3(8192), blk, 0, stream>>>(x, xb, BSD);
  cvt_f32_bf16<<<dim3(512), blk, 0, stream>>>(Wq, Wqkvb, DD);
  cvt_f32_bf16<<<dim3(512), blk, 0, stream>>>(Wk, Wqkvb + DD, DD);
  cvt_f32_bf16<<<dim3(512), blk, 0, stream>>>(Wv, Wqkvb + 2 * DD, DD);
  // 1: fused QKV projection (M=16384, N=3072, K=1024)
  gemm_bt<EP_QKV><<<dim3(64, 12, 1), gblk, 0, stream>>>(
      xb, Wqkvb, qb, 3072, 1024, 0, 0, 0, 0, nullptr, nullptr, 1.f);
  // 2: scores = q@k^T / 32 (per batch: M=N=2048, K=1024)
  gemm_bt<EP_BF16><<<dim3(8, 8, 8), gblk, 0, stream>>>(
      qb, kb, sP, 2048, 1024, SD, SD, SS, 0, nullptr, nullptr, 0.03125f);
  // 2b: FFN weights into kb region (kb dead now)
  cvt_f32_bf16<<<dim3(1024), blk, 0, stream>>>(W1, W1b, HD);
  cvt_f32_bf16<<<dim3(1024), blk, 0, stream>>>(W2, W2b, HD);
  // 3: softmax
  softmax_inplace<<<dim3(16384), blk, 0, stream>>>(sP);
  // 4: attn_out + x (per batch: M=2048, N=1024, K=2048)
  gemm_bt<EP_PV><<<dim3(8, 4, 8), gblk, 0, stream>>>(
      sP, vTb, r1, 1024, 2048, SS, DS, SD, SD, nullptr, x, 1.f);
  // 5: LN1 -> h (fp32, in d_out) + hb (bf16, aliases qb)
  ln_row<0><<<dim3(16384), blk, 0, stream>>>(r1, g1, be1, h, hb);
  // 6: ff1 = relu(hb@W1^T + b1) (M=16384, N=2048, K=1024)
  gemm_bt<EP_FF1><<<dim3(64, 8, 1), gblk, 0, stream>>>(
      hb, W1b, sP, 2048, 1024, 0, 0, 0, 0, b1, nullptr, 1.f);
  // 7: res2 = ff1@W2^T + b2 + h (M=16384, N=1024, K=2048)
  gemm_bt<EP_FF2><<<dim3(64, 4, 1), gblk, 0, stream>>>(
      sP, W2b, r1, 1024, 2048, 0, 0, 0, 0, b2, h, 1.f);
  // 8: LN2 -> out (overwrites h)
  ln_row<1><<<dim3(16384), blk, 0, stream>>>(r1, g2, be2, out, nullptr);
}

// Round 21
// 451.824 us; speedup vs baseline: 1.3868x; 1.0969x over previous
//
#include <hip/hip_runtime.h>
#include <hip/hip_bf16.h>

// ---------------------------------------------------------------------------
// MiniTransformer: B=8,S=2048,D=1024,H=2048, fp32 in/out, bf16 MFMA inside.
// R21 = R15 GEMM schedule (best, 493us) + DTYPE-THINNED intermediates:
//   - PV writes r1 as bf16 (was fp32)          -33.5 MB write, -33.5 read
//   - LN1 emits ONLY bf16 hb (fp32 h dropped)  -67 MB write
//   - FF2 residual = hb (bf16, = FF1's input)  -33.5 MB read
//   - FF2 writes r2 as bf16                    -33.5+33.5 MB (w+LN2 r)
//   Total ~234 MB less traffic (~35us). Numerics: 3 extra bf16 roundings on
//   O(1) residual tensors; headroom 0.031 vs 0.1075 threshold.
// GEMM: 256x256 tile, BK=64, 8 waves (2Mx4N), 2-dbuf LDS (128KB),
// 4 phases/K-tile, 2 barriers/K-tile, counted vmcnt(4) ledger, compiler
// lgkm waits, natural linearization, XOR LDS layout (0 conflicts).
// Pipeline: cvt, QKV(fused,vT), scores, cvtW, softmax, PV+res(bf16 out),
// LN1(bf16->bf16), FF1(bias+relu), FF2(bias+bf16 res, bf16 out),
// LN2(bf16->fp32 out). Scratch 201,326,592 B.
// ---------------------------------------------------------------------------

typedef __attribute__((ext_vector_type(4))) float  f32x4;
typedef __attribute__((ext_vector_type(8))) short  short8;
typedef __attribute__((ext_vector_type(4))) short  short4v;
typedef __attribute__((ext_vector_type(8))) __bf16 bf16x8;
typedef unsigned short ushort_t;

static __device__ __forceinline__ unsigned short f2bf(float f) {
  unsigned u = __builtin_bit_cast(unsigned, f);
  u += 0x7fffu + ((u >> 16) & 1u);  // RNE
  return (unsigned short)(u >> 16);
}
static __device__ __forceinline__ float bf2f(unsigned short u) {
  return __builtin_bit_cast(float, (unsigned)u << 16);
}

#define GLDS16(g, l)                                                        \
  __builtin_amdgcn_global_load_lds(                                         \
      (const __attribute__((address_space(1))) void*)(g),                   \
      (__attribute__((address_space(3))) void*)(l), 16, 0, 0)

// ---------------------------------------------------------------------------
__global__ __launch_bounds__(256) void cvt_f32_bf16(
    const float* __restrict__ in, ushort_t* __restrict__ out, long n) {
  long i = ((long)blockIdx.x * 256 + threadIdx.x) * 8;
  if (i >= n) return;
  f32x4 a = *(const f32x4*)(in + i);
  f32x4 b = *(const f32x4*)(in + i + 4);
  short8 t;
  t[0] = (short)f2bf(a.x); t[1] = (short)f2bf(a.y);
  t[2] = (short)f2bf(a.z); t[3] = (short)f2bf(a.w);
  t[4] = (short)f2bf(b.x); t[5] = (short)f2bf(b.y);
  t[6] = (short)f2bf(b.z); t[7] = (short)f2bf(b.w);
  *(short8*)(out + i) = t;
}

// ---------------------------------------------------------------------------
enum { EP_QKV = 0, EP_BF16 = 1, EP_PV = 2, EP_FF1 = 3, EP_FF2 = 4 };

constexpr long BSDc = 8L * 2048 * 1024;

template <int EPI>
__global__ __launch_bounds__(512, 2) void gemm_bt(
    const ushort_t* __restrict__ A, const ushort_t* __restrict__ B,
    void* __restrict__ C, int N, int K, long sA, long sB, long sC, long sRes,
    const float* __restrict__ bias, const void* __restrict__ res,
    float scale) {
  // [dbuf][half][128 rows x 64 k] per operand: 2*2*16KB*2 = 128KB.
  __shared__ __align__(16) ushort_t As[2][2][8192];
  __shared__ __align__(16) ushort_t Bs[2][2][8192];
  const int tid  = threadIdx.x;
  const int lane = tid & 63;
  const int w    = tid >> 6;        // 0..7
  const int wm   = w >> 2;          // 0..1 : wave row-half (128 rows)
  const int wn   = w & 3;           // 0..3 : wave col (64 cols)
  const int l15  = lane & 15;
  const int hi   = lane >> 4;       // 0..3 : 8-elem k-chunk
  const long bz  = blockIdx.z;
  const long m0  = (long)blockIdx.x * 256;
  const long n0  = (long)blockIdx.y * 256;
  const ushort_t* Ab = A + bz * sA;
  const ushort_t* Bb = B + bz * sB;

  // Staging source (inverse of read-side XOR): thread handles phys chunks
  // tid and tid+512 of each 1024-chunk half. row = P>>3, slot = (P&7)^(row&7).
  const int srow = tid >> 3;
  const int sc   = (tid & 7) ^ (srow & 7);
  const long offA0 = (m0 + srow) * (long)K + sc * 8;
  const long offB0 = (n0 + srow) * (long)K + sc * 8;
  const int dst0 = w * 512;
  const int dst1 = 4096 + w * 512;

#define STAGE_A(t, h)                                                       \
  {                                                                         \
    const long o_ = (long)(t) * 64 + (long)(h) * 128 * K;                   \
    ushort_t* l_ = &As[(t) & 1][h][0];                                      \
    GLDS16(Ab + offA0 + o_, l_ + dst0);                                     \
    GLDS16(Ab + offA0 + 64 * (long)K + o_, l_ + dst1);                      \
  }
#define STAGE_B(t, h)                                                       \
  {                                                                         \
    const long o_ = (long)(t) * 64 + (long)(h) * 128 * K;                   \
    ushort_t* l_ = &Bs[(t) & 1][h][0];                                      \
    GLDS16(Bb + offB0 + o_, l_ + dst0);                                     \
    GLDS16(Bb + offB0 + 64 * (long)K + o_, l_ + dst1);                      \
  }

  // Read-side swizzled byte offsets (k-step 0 / 1), lane-constant.
  const int ab0 = l15 * 128 + ((hi) ^ (l15 & 7)) * 16;
  const int ab1 = l15 * 128 + ((4 + hi) ^ (l15 & 7)) * 16;

#define READ_A(ai)                                                          \
  _Pragma("unroll") for (int i = 0; i < 4; ++i) {                           \
    afr[i][0] = *(const short8*)(Ah + (ai) * 8192 + i * 2048 + ab0);        \
    afr[i][1] = *(const short8*)(Ah + (ai) * 8192 + i * 2048 + ab1);        \
  }
#define READ_B(bj)                                                          \
  _Pragma("unroll") for (int j = 0; j < 2; ++j) {                           \
    bfr[bj][j][0] = *(const short8*)(Bh + (bj) * 4096 + j * 2048 + ab0);    \
    bfr[bj][j][1] = *(const short8*)(Bh + (bj) * 4096 + j * 2048 + ab1);    \
  }
#define QMFMA(ib, jb, bsel)                                                 \
  _Pragma("unroll") for (int i = 0; i < 4; ++i)                             \
  _Pragma("unroll") for (int j = 0; j < 2; ++j)                             \
  _Pragma("unroll") for (int ks = 0; ks < 2; ++ks)                          \
    acc[(ib) + i][(jb) + j] = __builtin_amdgcn_mfma_f32_16x16x32_bf16(      \
        __builtin_bit_cast(bf16x8, afr[i][ks]),                             \
        __builtin_bit_cast(bf16x8, bfr[bsel][j][ks]),                       \
        acc[(ib) + i][(jb) + j], 0, 0, 0);

  f32x4 acc[8][4] = {};
  const int NT = K >> 6;  // K-tiles of 64 (16 or 32)

  // Prologue ring: (0).B0,B1,A0,A1,(1).B0,B1 = 12 loads; retire tile 0.
  STAGE_B(0, 0) STAGE_B(0, 1) STAGE_A(0, 0) STAGE_A(0, 1)
  STAGE_B(1, 0) STAGE_B(1, 1)
  asm volatile("s_waitcnt vmcnt(4)" ::: "memory");
  __builtin_amdgcn_sched_barrier(0);
  __builtin_amdgcn_s_barrier();
  __builtin_amdgcn_sched_barrier(0);

  for (int u = 0; u < NT; ++u) {
    const int d = u & 1;
    const char* Ah = (const char*)&As[d][wm][0];
    const char* Bh = (const char*)&Bs[d][wn >> 1][0] + (wn & 1) * 8192;
    short8 afr[4][2], bfr[2][2][2];
    // ---- phase 1: quadrant A0 x B0 (no bars: buf d confirmed at entry) ----
    READ_A(0)
    READ_B(0)
    if (u + 1 < NT) STAGE_A(u + 1, 0)
    QMFMA(0, 0, 0)
    // ---- phase 2: quadrant A0 x B1 ----
    READ_B(1)
    if (u + 1 < NT) STAGE_A(u + 1, 1)
    QMFMA(0, 2, 1)
    __builtin_amdgcn_s_barrier();  // all waves done reading B-halves of buf d
    // ---- phase 3: quadrant A1 x B1 (stage may overwrite buf d B0 now) ----
    READ_A(1)
    if (u + 2 < NT) STAGE_B(u + 2, 0)
    QMFMA(4, 2, 1)
    // ---- phase 4: quadrant A1 x B0 (all from regs) ----
    if (u + 2 < NT) STAGE_B(u + 2, 1)
    QMFMA(4, 0, 0)
    // ---- K-tile boundary: tile u+1 must be fully resident ----
    if (u + 1 < NT) {
      if (u + 2 < NT) {
        asm volatile("s_waitcnt vmcnt(4)" ::: "memory");
      } else {
        asm volatile("s_waitcnt vmcnt(0)" ::: "memory");
      }
      __builtin_amdgcn_sched_barrier(0);
      __builtin_amdgcn_s_barrier();
      __builtin_amdgcn_sched_barrier(0);
    }
  }
#undef STAGE_A
#undef STAGE_B
#undef READ_A
#undef READ_B
#undef QMFMA

  // Epilogue. C/D layout: col = lane&15, row = (lane>>4)*4 + reg.
  const int rb0 = hi << 2;
  const int cl  = l15;
#pragma unroll
  for (int i = 0; i < 8; ++i) {
#pragma unroll
    for (int j = 0; j < 4; ++j) {
      long gmb = m0 + wm * 128 + i * 16 + rb0;
      long gc  = n0 + wn * 64 + j * 16 + cl;
      if constexpr (EPI == EP_QKV) {
        long which = gc >> 10;  // 0=q, 1=k, 2=v (uniform per block)
        long col   = gc & 1023;
        if (which == 2) {
          long bb = gmb >> 11, s = gmb & 2047;
          short4v pk;
#pragma unroll
          for (int r = 0; r < 4; ++r) pk[r] = (short)f2bf(acc[i][j][r]);
          *(short4v*)((ushort_t*)C + 2 * BSDc + ((bb << 10) + col) * 2048 + s) =
              pk;
        } else {
#pragma unroll
          for (int r = 0; r < 4; ++r)
            ((ushort_t*)C)[which * BSDc + (gmb + r) * 1024 + col] =
                f2bf(acc[i][j][r]);
        }
      } else {
#pragma unroll
        for (int r = 0; r < 4; ++r) {
          long gm = gmb + r;
          float v = acc[i][j][r] * scale;
          if constexpr (EPI == EP_BF16) {
            ((ushort_t*)C)[bz * sC + gm * N + gc] = f2bf(v);
          } else if constexpr (EPI == EP_PV) {
            // residual x is fp32 input; OUTPUT is bf16 now.
            v += ((const float*)res)[bz * sRes + gm * N + gc];
            ((ushort_t*)C)[bz * sC + gm * N + gc] = f2bf(v);
          } else if constexpr (EPI == EP_FF1) {
            v += bias[gc];
            v = v > 0.f ? v : 0.f;
            ((ushort_t*)C)[gm * N + gc] = f2bf(v);
          } else {  // EP_FF2: residual hb is bf16; OUTPUT bf16.
            v += bias[gc] + bf2f(((const ushort_t*)res)[gm * N + gc]);
            ((ushort_t*)C)[gm * N + gc] = f2bf(v);
          }
        }
      }
    }
  }
}

// ---------------------------------------------------------------------------
// Row softmax, in place on bf16 (B*S rows of 2048). 256 thr, 8 el/thread.
// ---------------------------------------------------------------------------
__global__ __launch_bounds__(256) void softmax_inplace(
    ushort_t* __restrict__ P) {
  __shared__ float rmax[4], rsum[4];
  const int tid   = threadIdx.x;
  const long base = (long)blockIdx.x * 2048;
  short8 sv = *(const short8*)(P + base + tid * 8);
  float v[8];
#pragma unroll
  for (int j = 0; j < 8; ++j) v[j] = bf2f((unsigned short)sv[j]);
  float mx = v[0];
#pragma unroll
  for (int j = 1; j < 8; ++j) mx = fmaxf(mx, v[j]);
#pragma unroll
  for (int off = 32; off; off >>= 1) mx = fmaxf(mx, __shfl_down(mx, off, 64));
  if ((tid & 63) == 0) rmax[tid >> 6] = mx;
  __syncthreads();
  mx = fmaxf(fmaxf(rmax[0], rmax[1]), fmaxf(rmax[2], rmax[3]));
  float s = 0.f;
#pragma unroll
  for (int j = 0; j < 8; ++j) {
    v[j] = __expf(v[j] - mx);
    s += v[j];
  }
#pragma unroll
  for (int off = 32; off; off >>= 1) s += __shfl_down(s, off, 64);
  if ((tid & 63) == 0) rsum[tid >> 6] = s;
  __syncthreads();
  s = (rsum[0] + rsum[1]) + (rsum[2] + rsum[3]);
  float inv = 1.f / s;
  short8 o;
#pragma unroll
  for (int j = 0; j < 8; ++j) o[j] = (short)f2bf(v[j] * inv);
  *(short8*)(P + base + tid * 8) = o;
}

// ---------------------------------------------------------------------------
// Row LayerNorm over D=1024, bf16 input. MODE 0: bf16 out; MODE 1: fp32 out.
// ---------------------------------------------------------------------------
template <int MODE>
__global__ __launch_bounds__(256) void ln_row_b(const ushort_t* __restrict__ X,
                                                const float* __restrict__ g,
                                                const float* __restrict__ be,
                                                void* __restrict__ Y) {
  __shared__ float rs[4], rq[4];
  const int tid   = threadIdx.x;
  const long base = (long)blockIdx.x << 10;
  short4v sv = *(const short4v*)(X + base + tid * 4);
  float v0 = bf2f((unsigned short)sv[0]);
  float v1 = bf2f((unsigned short)sv[1]);
  float v2 = bf2f((unsigned short)sv[2]);
  float v3 = bf2f((unsigned short)sv[3]);
  float s = v0 + v1 + v2 + v3;
  float q = v0 * v0 + v1 * v1 + v2 * v2 + v3 * v3;
#pragma unroll
  for (int off = 32; off; off >>= 1) {
    s += __shfl_down(s, off, 64);
    q += __shfl_down(q, off, 64);
  }
  if ((tid & 63) == 0) {
    rs[tid >> 6] = s;
    rq[tid >> 6] = q;
  }
  __syncthreads();
  s = (rs[0] + rs[1]) + (rs[2] + rs[3]);
  q = (rq[0] + rq[1]) + (rq[2] + rq[3]);
  float mu   = s * (1.f / 1024.f);
  float var  = q * (1.f / 1024.f) - mu * mu;
  float rstd = rsqrtf(var + 1e-5f);
  int c    = tid * 4;
  f32x4 gg = *(const f32x4*)(g + c);
  f32x4 bb = *(const f32x4*)(be + c);
  float y0 = (v0 - mu) * rstd * gg.x + bb.x;
  float y1 = (v1 - mu) * rstd * gg.y + bb.y;
  float y2 = (v2 - mu) * rstd * gg.z + bb.z;
  float y3 = (v3 - mu) * rstd * gg.w + bb.w;
  if constexpr (MODE == 0) {
    short4v ob;
    ob[0] = (short)f2bf(y0);
    ob[1] = (short)f2bf(y1);
    ob[2] = (short)f2bf(y2);
    ob[3] = (short)f2bf(y3);
    *(short4v*)((ushort_t*)Y + base + c) = ob;
  } else {
    f32x4 yo;
    yo.x = y0; yo.y = y1; yo.z = y2; yo.w = y3;
    *(f32x4*)((float*)Y + base + c) = yo;
  }
}

// ---------------------------------------------------------------------------
extern "C" void kernel_launch(void* const* d_in, const int* in_sizes, int n_in,
                              void* d_out, int out_size, void* d_ws,
                              size_t ws_size, hipStream_t stream) {
  const float* x   = (const float*)d_in[0];
  const float* Wq  = (const float*)d_in[1];
  const float* Wk  = (const float*)d_in[2];
  const float* Wv  = (const float*)d_in[3];
  const float* W1  = (const float*)d_in[4];
  const float* b1  = (const float*)d_in[5];
  const float* W2  = (const float*)d_in[6];
  const float* b2  = (const float*)d_in[7];
  const float* g1  = (const float*)d_in[8];
  const float* be1 = (const float*)d_in[9];
  const float* g2  = (const float*)d_in[10];
  const float* be2 = (const float*)d_in[11];
  float* out = (float*)d_out;

  constexpr long BSD = 8L * 2048 * 1024;
  constexpr long BSS = 8L * 2048 * 2048;
  constexpr long DD  = 1024L * 1024;
  constexpr long HD  = 2048L * 1024;

  // Scratch: qb | kb | vTb | sP | r1b  (all bf16) = 201,326,592 bytes.
  ushort_t* qb  = (ushort_t*)d_ws;   // q; reused as hb after scores GEMM
  ushort_t* kb  = qb + BSD;          // k; reused as W1b/W2b after scores
  ushort_t* vTb = kb + BSD;          // (B,D,S)
  ushort_t* sP  = vTb + BSD;         // xb -> scores -> P -> ff1 (BSS)
  ushort_t* r1b = sP + BSS;          // attn+x (bf16) -> r2 (bf16)

  ushort_t* xb    = sP;              // dead before scores written
  ushort_t* Wqkvb = r1b;             // [3072,1024] bf16; dead before PV
  ushort_t* W1b   = kb;              // converted after scores GEMM
  ushort_t* W2b   = kb + HD;
  ushort_t* hb    = qb;              // LN1 output (bf16) = FF1 input + FF2 res

  dim3 blk(256), gblk(512);
  const long SD = 2048L * 1024, SS = 2048L * 2048, DS = 1024L * 2048;

  // 0: conversions (Wqkvb lives in r1b region, 3072*1024*2B = 6.3MB << r1b)
  cvt_f32_bf16<<<dim3(8192), blk, 0, stream>>>(x, xb, BSD);
  cvt_f32_bf16<<<dim3(512), blk, 0, stream>>>(Wq, Wqkvb, DD);
  cvt_f32_bf16<<<dim3(512), blk, 0, stream>>>(Wk, Wqkvb + DD, DD);
  cvt_f32_bf16<<<dim3(512), blk, 0, stream>>>(Wv, Wqkvb + 2 * DD, DD);
  // 1: fused QKV projection (M=16384, N=3072, K=1024)
  gemm_bt<EP_QKV><<<dim3(64, 12, 1), gblk, 0, stream>>>(
      xb, Wqkvb, qb, 3072, 1024, 0, 0, 0, 0, nullptr, nullptr, 1.f);
  // 2: scores = q@k^T / 32 (per batch: M=N=2048, K=1024)
  gemm_bt<EP_BF16><<<dim3(8, 8, 8), gblk, 0, stream>>>(
      qb, kb, sP, 2048, 1024, SD, SD, SS, 0, nullptr, nullptr, 0.03125f);
  // 2b: FFN weights into kb region (kb dead now)
  cvt_f32_bf16<<<dim3(1024), blk, 0, stream>>>(W1, W1b, HD);
  cvt_f32_bf16<<<dim3(1024), blk, 0, stream>>>(W2, W2b, HD);
  // 3: softmax
  softmax_inplace<<<dim3(16384), blk, 0, stream>>>(sP);
  // 4: attn_out + x -> r1b (bf16) (per batch: M=2048, N=1024, K=2048)
  gemm_bt<EP_PV><<<dim3(8, 4, 8), gblk, 0, stream>>>(
      sP, vTb, r1b, 1024, 2048, SS, DS, SD, SD, nullptr, x, 1.f);
  // 5: LN1: r1b (bf16) -> hb (bf16, aliases qb)
  ln_row_b<0><<<dim3(16384), blk, 0, stream>>>(r1b, g1, be1, hb);
  // 6: ff1 = relu(hb@W1^T + b1) (M=16384, N=2048, K=1024)
  gemm_bt<EP_FF1><<<dim3(64, 8, 1), gblk, 0, stream>>>(
      hb, W1b, sP, 2048, 1024, 0, 0, 0, 0, b1, nullptr, 1.f);
  // 7: r2 = ff1@W2^T + b2 + hb -> r1b (bf16; r1b dead after LN1)
  gemm_bt<EP_FF2><<<dim3(64, 4, 1), gblk, 0, stream>>>(
      sP, W2b, r1b, 1024, 2048, 0, 0, 0, 0, b2, hb, 1.f);
  // 8: LN2: r1b (bf16) -> out (fp32)
  ln_row_b<1><<<dim3(16384), blk, 0, stream>>>(r1b, g2, be2, out);
}

// Round 22
// 451.114 us; speedup vs baseline: 1.3890x; 1.0016x over previous
//
#include <hip/hip_runtime.h>
#include <hip/hip_bf16.h>

// ---------------------------------------------------------------------------
// MiniTransformer: B=8,S=2048,D=1024,H=2048, fp32 in/out, bf16 MFMA inside.
// R22 = R21 + dedicated xb buffer so PV's residual reads bf16 xb (not fp32
// x): -33.5 MB traffic. Scratch back to 234,881,024 B (proven R2-R20).
// All-bf16 intermediate chain (R21): PV->r1b bf16, LN1->hb bf16 only,
// FF2 res=hb bf16, FF2 out bf16, LN2 bf16->fp32 out.
// GEMM (R15 schedule, plateau 33% MfmaUtil): 256x256 tile, BK=64, 8 waves,
// 2-dbuf 128KB LDS, 4 phases/K-tile, 2 barriers/K-tile, counted vmcnt(4)
// ledger, compiler lgkm waits, XOR LDS layout (0 conflicts).
// Pipeline: cvt, QKV(fused,vT), scores, cvtW, softmax, PV+bf16res, LN1,
// FF1(bias+relu), FF2(bias+bf16res), LN2.
// ---------------------------------------------------------------------------

typedef __attribute__((ext_vector_type(4))) float  f32x4;
typedef __attribute__((ext_vector_type(8))) short  short8;
typedef __attribute__((ext_vector_type(4))) short  short4v;
typedef __attribute__((ext_vector_type(8))) __bf16 bf16x8;
typedef unsigned short ushort_t;

static __device__ __forceinline__ unsigned short f2bf(float f) {
  unsigned u = __builtin_bit_cast(unsigned, f);
  u += 0x7fffu + ((u >> 16) & 1u);  // RNE
  return (unsigned short)(u >> 16);
}
static __device__ __forceinline__ float bf2f(unsigned short u) {
  return __builtin_bit_cast(float, (unsigned)u << 16);
}

#define GLDS16(g, l)                                                        \
  __builtin_amdgcn_global_load_lds(                                         \
      (const __attribute__((address_space(1))) void*)(g),                   \
      (__attribute__((address_space(3))) void*)(l), 16, 0, 0)

// ---------------------------------------------------------------------------
__global__ __launch_bounds__(256) void cvt_f32_bf16(
    const float* __restrict__ in, ushort_t* __restrict__ out, long n) {
  long i = ((long)blockIdx.x * 256 + threadIdx.x) * 8;
  if (i >= n) return;
  f32x4 a = *(const f32x4*)(in + i);
  f32x4 b = *(const f32x4*)(in + i + 4);
  short8 t;
  t[0] = (short)f2bf(a.x); t[1] = (short)f2bf(a.y);
  t[2] = (short)f2bf(a.z); t[3] = (short)f2bf(a.w);
  t[4] = (short)f2bf(b.x); t[5] = (short)f2bf(b.y);
  t[6] = (short)f2bf(b.z); t[7] = (short)f2bf(b.w);
  *(short8*)(out + i) = t;
}

// ---------------------------------------------------------------------------
enum { EP_QKV = 0, EP_BF16 = 1, EP_PV = 2, EP_FF1 = 3, EP_FF2 = 4 };

constexpr long BSDc = 8L * 2048 * 1024;

template <int EPI>
__global__ __launch_bounds__(512, 2) void gemm_bt(
    const ushort_t* __restrict__ A, const ushort_t* __restrict__ B,
    void* __restrict__ C, int N, int K, long sA, long sB, long sC, long sRes,
    const float* __restrict__ bias, const void* __restrict__ res,
    float scale) {
  // [dbuf][half][128 rows x 64 k] per operand: 2*2*16KB*2 = 128KB.
  __shared__ __align__(16) ushort_t As[2][2][8192];
  __shared__ __align__(16) ushort_t Bs[2][2][8192];
  const int tid  = threadIdx.x;
  const int lane = tid & 63;
  const int w    = tid >> 6;        // 0..7
  const int wm   = w >> 2;          // 0..1 : wave row-half (128 rows)
  const int wn   = w & 3;           // 0..3 : wave col (64 cols)
  const int l15  = lane & 15;
  const int hi   = lane >> 4;       // 0..3 : 8-elem k-chunk
  const long bz  = blockIdx.z;
  const long m0  = (long)blockIdx.x * 256;
  const long n0  = (long)blockIdx.y * 256;
  const ushort_t* Ab = A + bz * sA;
  const ushort_t* Bb = B + bz * sB;

  // Staging source (inverse of read-side XOR): thread handles phys chunks
  // tid and tid+512 of each 1024-chunk half. row = P>>3, slot = (P&7)^(row&7).
  const int srow = tid >> 3;
  const int sc   = (tid & 7) ^ (srow & 7);
  const long offA0 = (m0 + srow) * (long)K + sc * 8;
  const long offB0 = (n0 + srow) * (long)K + sc * 8;
  const int dst0 = w * 512;
  const int dst1 = 4096 + w * 512;

#define STAGE_A(t, h)                                                       \
  {                                                                         \
    const long o_ = (long)(t) * 64 + (long)(h) * 128 * K;                   \
    ushort_t* l_ = &As[(t) & 1][h][0];                                      \
    GLDS16(Ab + offA0 + o_, l_ + dst0);                                     \
    GLDS16(Ab + offA0 + 64 * (long)K + o_, l_ + dst1);                      \
  }
#define STAGE_B(t, h)                                                       \
  {                                                                         \
    const long o_ = (long)(t) * 64 + (long)(h) * 128 * K;                   \
    ushort_t* l_ = &Bs[(t) & 1][h][0];                                      \
    GLDS16(Bb + offB0 + o_, l_ + dst0);                                     \
    GLDS16(Bb + offB0 + 64 * (long)K + o_, l_ + dst1);                      \
  }

  // Read-side swizzled byte offsets (k-step 0 / 1), lane-constant.
  const int ab0 = l15 * 128 + ((hi) ^ (l15 & 7)) * 16;
  const int ab1 = l15 * 128 + ((4 + hi) ^ (l15 & 7)) * 16;

#define READ_A(ai)                                                          \
  _Pragma("unroll") for (int i = 0; i < 4; ++i) {                           \
    afr[i][0] = *(const short8*)(Ah + (ai) * 8192 + i * 2048 + ab0);        \
    afr[i][1] = *(const short8*)(Ah + (ai) * 8192 + i * 2048 + ab1);        \
  }
#define READ_B(bj)                                                          \
  _Pragma("unroll") for (int j = 0; j < 2; ++j) {                           \
    bfr[bj][j][0] = *(const short8*)(Bh + (bj) * 4096 + j * 2048 + ab0);    \
    bfr[bj][j][1] = *(const short8*)(Bh + (bj) * 4096 + j * 2048 + ab1);    \
  }
#define QMFMA(ib, jb, bsel)                                                 \
  _Pragma("unroll") for (int i = 0; i < 4; ++i)                             \
  _Pragma("unroll") for (int j = 0; j < 2; ++j)                             \
  _Pragma("unroll") for (int ks = 0; ks < 2; ++ks)                          \
    acc[(ib) + i][(jb) + j] = __builtin_amdgcn_mfma_f32_16x16x32_bf16(      \
        __builtin_bit_cast(bf16x8, afr[i][ks]),                             \
        __builtin_bit_cast(bf16x8, bfr[bsel][j][ks]),                       \
        acc[(ib) + i][(jb) + j], 0, 0, 0);

  f32x4 acc[8][4] = {};
  const int NT = K >> 6;  // K-tiles of 64 (16 or 32)

  // Prologue ring: (0).B0,B1,A0,A1,(1).B0,B1 = 12 loads; retire tile 0.
  STAGE_B(0, 0) STAGE_B(0, 1) STAGE_A(0, 0) STAGE_A(0, 1)
  STAGE_B(1, 0) STAGE_B(1, 1)
  asm volatile("s_waitcnt vmcnt(4)" ::: "memory");
  __builtin_amdgcn_sched_barrier(0);
  __builtin_amdgcn_s_barrier();
  __builtin_amdgcn_sched_barrier(0);

  for (int u = 0; u < NT; ++u) {
    const int d = u & 1;
    const char* Ah = (const char*)&As[d][wm][0];
    const char* Bh = (const char*)&Bs[d][wn >> 1][0] + (wn & 1) * 8192;
    short8 afr[4][2], bfr[2][2][2];
    // ---- phase 1: quadrant A0 x B0 (no bars: buf d confirmed at entry) ----
    READ_A(0)
    READ_B(0)
    if (u + 1 < NT) STAGE_A(u + 1, 0)
    QMFMA(0, 0, 0)
    // ---- phase 2: quadrant A0 x B1 ----
    READ_B(1)
    if (u + 1 < NT) STAGE_A(u + 1, 1)
    QMFMA(0, 2, 1)
    __builtin_amdgcn_s_barrier();  // all waves done reading B-halves of buf d
    // ---- phase 3: quadrant A1 x B1 (stage may overwrite buf d B0 now) ----
    READ_A(1)
    if (u + 2 < NT) STAGE_B(u + 2, 0)
    QMFMA(4, 2, 1)
    // ---- phase 4: quadrant A1 x B0 (all from regs) ----
    if (u + 2 < NT) STAGE_B(u + 2, 1)
    QMFMA(4, 0, 0)
    // ---- K-tile boundary: tile u+1 must be fully resident ----
    if (u + 1 < NT) {
      if (u + 2 < NT) {
        asm volatile("s_waitcnt vmcnt(4)" ::: "memory");
      } else {
        asm volatile("s_waitcnt vmcnt(0)" ::: "memory");
      }
      __builtin_amdgcn_sched_barrier(0);
      __builtin_amdgcn_s_barrier();
      __builtin_amdgcn_sched_barrier(0);
    }
  }
#undef STAGE_A
#undef STAGE_B
#undef READ_A
#undef READ_B
#undef QMFMA

  // Epilogue. C/D layout: col = lane&15, row = (lane>>4)*4 + reg.
  const int rb0 = hi << 2;
  const int cl  = l15;
#pragma unroll
  for (int i = 0; i < 8; ++i) {
#pragma unroll
    for (int j = 0; j < 4; ++j) {
      long gmb = m0 + wm * 128 + i * 16 + rb0;
      long gc  = n0 + wn * 64 + j * 16 + cl;
      if constexpr (EPI == EP_QKV) {
        long which = gc >> 10;  // 0=q, 1=k, 2=v (uniform per block)
        long col   = gc & 1023;
        if (which == 2) {
          long bb = gmb >> 11, s = gmb & 2047;
          short4v pk;
#pragma unroll
          for (int r = 0; r < 4; ++r) pk[r] = (short)f2bf(acc[i][j][r]);
          *(short4v*)((ushort_t*)C + 2 * BSDc + ((bb << 10) + col) * 2048 + s) =
              pk;
        } else {
#pragma unroll
          for (int r = 0; r < 4; ++r)
            ((ushort_t*)C)[which * BSDc + (gmb + r) * 1024 + col] =
                f2bf(acc[i][j][r]);
        }
      } else {
#pragma unroll
        for (int r = 0; r < 4; ++r) {
          long gm = gmb + r;
          float v = acc[i][j][r] * scale;
          if constexpr (EPI == EP_BF16) {
            ((ushort_t*)C)[bz * sC + gm * N + gc] = f2bf(v);
          } else if constexpr (EPI == EP_PV) {
            // residual xb is bf16 now; OUTPUT bf16.
            v += bf2f(((const ushort_t*)res)[bz * sRes + gm * N + gc]);
            ((ushort_t*)C)[bz * sC + gm * N + gc] = f2bf(v);
          } else if constexpr (EPI == EP_FF1) {
            v += bias[gc];
            v = v > 0.f ? v : 0.f;
            ((ushort_t*)C)[gm * N + gc] = f2bf(v);
          } else {  // EP_FF2: residual hb is bf16; OUTPUT bf16.
            v += bias[gc] + bf2f(((const ushort_t*)res)[gm * N + gc]);
            ((ushort_t*)C)[gm * N + gc] = f2bf(v);
          }
        }
      }
    }
  }
}

// ---------------------------------------------------------------------------
// Row softmax, in place on bf16 (B*S rows of 2048). 256 thr, 8 el/thread.
// ---------------------------------------------------------------------------
__global__ __launch_bounds__(256) void softmax_inplace(
    ushort_t* __restrict__ P) {
  __shared__ float rmax[4], rsum[4];
  const int tid   = threadIdx.x;
  const long base = (long)blockIdx.x * 2048;
  short8 sv = *(const short8*)(P + base + tid * 8);
  float v[8];
#pragma unroll
  for (int j = 0; j < 8; ++j) v[j] = bf2f((unsigned short)sv[j]);
  float mx = v[0];
#pragma unroll
  for (int j = 1; j < 8; ++j) mx = fmaxf(mx, v[j]);
#pragma unroll
  for (int off = 32; off; off >>= 1) mx = fmaxf(mx, __shfl_down(mx, off, 64));
  if ((tid & 63) == 0) rmax[tid >> 6] = mx;
  __syncthreads();
  mx = fmaxf(fmaxf(rmax[0], rmax[1]), fmaxf(rmax[2], rmax[3]));
  float s = 0.f;
#pragma unroll
  for (int j = 0; j < 8; ++j) {
    v[j] = __expf(v[j] - mx);
    s += v[j];
  }
#pragma unroll
  for (int off = 32; off; off >>= 1) s += __shfl_down(s, off, 64);
  if ((tid & 63) == 0) rsum[tid >> 6] = s;
  __syncthreads();
  s = (rsum[0] + rsum[1]) + (rsum[2] + rsum[3]);
  float inv = 1.f / s;
  short8 o;
#pragma unroll
  for (int j = 0; j < 8; ++j) o[j] = (short)f2bf(v[j] * inv);
  *(short8*)(P + base + tid * 8) = o;
}

// ---------------------------------------------------------------------------
// Row LayerNorm over D=1024, bf16 input. MODE 0: bf16 out; MODE 1: fp32 out.
// ---------------------------------------------------------------------------
template <int MODE>
__global__ __launch_bounds__(256) void ln_row_b(const ushort_t* __restrict__ X,
                                                const float* __restrict__ g,
                                                const float* __restrict__ be,
                                                void* __restrict__ Y) {
  __shared__ float rs[4], rq[4];
  const int tid   = threadIdx.x;
  const long base = (long)blockIdx.x << 10;
  short4v sv = *(const short4v*)(X + base + tid * 4);
  float v0 = bf2f((unsigned short)sv[0]);
  float v1 = bf2f((unsigned short)sv[1]);
  float v2 = bf2f((unsigned short)sv[2]);
  float v3 = bf2f((unsigned short)sv[3]);
  float s = v0 + v1 + v2 + v3;
  float q = v0 * v0 + v1 * v1 + v2 * v2 + v3 * v3;
#pragma unroll
  for (int off = 32; off; off >>= 1) {
    s += __shfl_down(s, off, 64);
    q += __shfl_down(q, off, 64);
  }
  if ((tid & 63) == 0) {
    rs[tid >> 6] = s;
    rq[tid >> 6] = q;
  }
  __syncthreads();
  s = (rs[0] + rs[1]) + (rs[2] + rs[3]);
  q = (rq[0] + rq[1]) + (rq[2] + rq[3]);
  float mu   = s * (1.f / 1024.f);
  float var  = q * (1.f / 1024.f) - mu * mu;
  float rstd = rsqrtf(var + 1e-5f);
  int c    = tid * 4;
  f32x4 gg = *(const f32x4*)(g + c);
  f32x4 bb = *(const f32x4*)(be + c);
  float y0 = (v0 - mu) * rstd * gg.x + bb.x;
  float y1 = (v1 - mu) * rstd * gg.y + bb.y;
  float y2 = (v2 - mu) * rstd * gg.z + bb.z;
  float y3 = (v3 - mu) * rstd * gg.w + bb.w;
  if constexpr (MODE == 0) {
    short4v ob;
    ob[0] = (short)f2bf(y0);
    ob[1] = (short)f2bf(y1);
    ob[2] = (short)f2bf(y2);
    ob[3] = (short)f2bf(y3);
    *(short4v*)((ushort_t*)Y + base + c) = ob;
  } else {
    f32x4 yo;
    yo.x = y0; yo.y = y1; yo.z = y2; yo.w = y3;
    *(f32x4*)((float*)Y + base + c) = yo;
  }
}

// ---------------------------------------------------------------------------
extern "C" void kernel_launch(void* const* d_in, const int* in_sizes, int n_in,
                              void* d_out, int out_size, void* d_ws,
                              size_t ws_size, hipStream_t stream) {
  const float* x   = (const float*)d_in[0];
  const float* Wq  = (const float*)d_in[1];
  const float* Wk  = (const float*)d_in[2];
  const float* Wv  = (const float*)d_in[3];
  const float* W1  = (const float*)d_in[4];
  const float* b1  = (const float*)d_in[5];
  const float* W2  = (const float*)d_in[6];
  const float* b2  = (const float*)d_in[7];
  const float* g1  = (const float*)d_in[8];
  const float* be1 = (const float*)d_in[9];
  const float* g2  = (const float*)d_in[10];
  const float* be2 = (const float*)d_in[11];
  float* out = (float*)d_out;

  constexpr long BSD = 8L * 2048 * 1024;
  constexpr long BSS = 8L * 2048 * 2048;
  constexpr long DD  = 1024L * 1024;
  constexpr long HD  = 2048L * 1024;

  // Scratch: qb | kb | vTb | sP | xbuf | r1b (all bf16) = 234,881,024 B.
  ushort_t* qb   = (ushort_t*)d_ws;  // q; reused as hb after scores GEMM
  ushort_t* kb   = qb + BSD;         // k; reused as W1b/W2b after scores
  ushort_t* vTb  = kb + BSD;         // (B,D,S)
  ushort_t* sP   = vTb + BSD;        // scores -> P -> ff1 (BSS)
  ushort_t* xbuf = sP + BSS;         // xb, stays live through PV
  ushort_t* r1b  = xbuf + BSD;       // attn+x (bf16) -> r2 (bf16)

  ushort_t* Wqkvb = r1b;             // [3072,1024] bf16; dead before PV
  ushort_t* W1b   = kb;              // converted after scores GEMM
  ushort_t* W2b   = kb + HD;
  ushort_t* hb    = qb;              // LN1 out (bf16) = FF1 input + FF2 res

  dim3 blk(256), gblk(512);
  const long SD = 2048L * 1024, SS = 2048L * 2048, DS = 1024L * 2048;

  // 0: conversions
  cvt_f32_bf16<<<dim3(8192), blk, 0, stream>>>(x, xbuf, BSD);
  cvt_f32_bf16<<<dim3(512), blk, 0, stream>>>(Wq, Wqkvb, DD);
  cvt_f32_bf16<<<dim3(512), blk, 0, stream>>>(Wk, Wqkvb + DD, DD);
  cvt_f32_bf16<<<dim3(512), blk, 0, stream>>>(Wv, Wqkvb + 2 * DD, DD);
  // 1: fused QKV projection (M=16384, N=3072, K=1024)
  gemm_bt<EP_QKV><<<dim3(64, 12, 1), gblk, 0, stream>>>(
      xbuf, Wqkvb, qb, 3072, 1024, 0, 0, 0, 0, nullptr, nullptr, 1.f);
  // 2: scores = q@k^T / 32 (per batch: M=N=2048, K=1024)
  gemm_bt<EP_BF16><<<dim3(8, 8, 8), gblk, 0, stream>>>(
      qb, kb, sP, 2048, 1024, SD, SD, SS, 0, nullptr, nullptr, 0.03125f);
  // 2b: FFN weights into kb region (kb dead now)
  cvt_f32_bf16<<<dim3(1024), blk, 0, stream>>>(W1, W1b, HD);
  cvt_f32_bf16<<<dim3(1024), blk, 0, stream>>>(W2, W2b, HD);
  // 3: softmax
  softmax_inplace<<<dim3(16384), blk, 0, stream>>>(sP);
  // 4: attn_out + xb -> r1b (bf16) (per batch: M=2048, N=1024, K=2048)
  gemm_bt<EP_PV><<<dim3(8, 4, 8), gblk, 0, stream>>>(
      sP, vTb, r1b, 1024, 2048, SS, DS, SD, SD, nullptr, xbuf, 1.f);
  // 5: LN1: r1b (bf16) -> hb (bf16, aliases qb)
  ln_row_b<0><<<dim3(16384), blk, 0, stream>>>(r1b, g1, be1, hb);
  // 6: ff1 = relu(hb@W1^T + b1) (M=16384, N=2048, K=1024)
  gemm_bt<EP_FF1><<<dim3(64, 8, 1), gblk, 0, stream>>>(
      hb, W1b, sP, 2048, 1024, 0, 0, 0, 0, b1, nullptr, 1.f);
  // 7: r2 = ff1@W2^T + b2 + hb -> r1b (bf16; r1b dead after LN1)
  gemm_bt<EP_FF2><<<dim3(64, 4, 1), gblk, 0, stream>>>(
      sP, W2b, r1b, 1024, 2048, 0, 0, 0, 0, b2, hb, 1.f);
  // 8: LN2: r1b (bf16) -> out (fp32)
  ln_row_b<1><<<dim3(16384), blk, 0, stream>>>(r1b, g2, be2, out);
}